// Round 1
// baseline (1719.548 us; speedup 1.0000x reference)
//
#include <hip/hip_runtime.h>
#include <math.h>

#define SK 7680          // 256 segments * 30 samples
#define NPTS 524288

// ---- workspace float offsets ----
#define WS_GQ_SUM   0
#define WS_GQ_SUM2  96
#define WS_GK_SUM   192
#define WS_GK_SUM2  288
#define WS_GQ_SCALE 384
#define WS_GQ_SHIFT 480
#define WS_GK_SCALE 576
#define WS_GK_SHIFT 672
#define WS_SEGX2    768                 // 256*96 raw view2 segment sums
#define WS_SEGG2    25344               // 256*96 head(view2) segment sums
#define WS_ANCHOR1  49920               // 256*96
#define WS_ANCHOR2  74496               // 256*96
#define WS_SAMPT    99072               // [96][7680] raw samples^T
#define WS_SAMP2T   836352              // [96][7680] head samples^T
// total = 1573632 floats = 6.0 MB

__device__ __forceinline__ void fma_row(float4& acc, const float4 x,
    const float4 w0, const float4 w1, const float4 w2, const float4 w3){
  acc.x = fmaf(x.x,w0.x, fmaf(x.y,w1.x, fmaf(x.z,w2.x, fmaf(x.w,w3.x, acc.x))));
  acc.y = fmaf(x.x,w0.y, fmaf(x.y,w1.y, fmaf(x.z,w2.y, fmaf(x.w,w3.y, acc.y))));
  acc.z = fmaf(x.x,w0.z, fmaf(x.y,w1.z, fmaf(x.z,w2.z, fmaf(x.w,w3.z, acc.z))));
  acc.w = fmaf(x.x,w0.w, fmaf(x.y,w1.w, fmaf(x.z,w2.w, fmaf(x.w,w3.w, acc.w))));
}

// W (96x96, row-major W[oc][k]) -> LDS transposed Ws[k*100+oc]
__device__ __forceinline__ void load_W(const float* __restrict__ W, float* Ws, int tid){
  #pragma unroll
  for (int i=0;i<12;i++){
    int f = i*768 + tid*4;            // 192 threads * 4 floats
    int oc = f/96, k = f%96;
    float4 w4 = *reinterpret_cast<const float4*>(W + f);
    Ws[(k+0)*100+oc]=w4.x; Ws[(k+1)*100+oc]=w4.y;
    Ws[(k+2)*100+oc]=w4.z; Ws[(k+3)*100+oc]=w4.w;
  }
}

// stage 32 contiguous rows (32*96 floats) into swizzled LDS tile Xs[32][100]
__device__ __forceinline__ void stage_rows(const float* __restrict__ src, float* Xs, int tid){
  #pragma unroll
  for (int i=0;i<4;i++){
    int f = i*768 + tid*4;
    int row = f/96, col = f%96;
    float4 v = *reinterpret_cast<const float4*>(src + f);
    *reinterpret_cast<float4*>(Xs + row*100 + (col ^ ((row>>2)<<2))) = v;
  }
}

// one 32-row x 96-oc tile: per-thread 4 rows x 4 ocs
__device__ __forceinline__ void gemm_tile(const float* Xs, const float* Ws,
    int ocg, int rowg, int r0, float4 acc[4]){
  const float4* Xs4 = reinterpret_cast<const float4*>(Xs);
  const float4* Ws4 = reinterpret_cast<const float4*>(Ws);
  acc[0]=acc[1]=acc[2]=acc[3]=make_float4(0.f,0.f,0.f,0.f);
  #pragma unroll 4
  for (int k4=0;k4<24;k4++){
    float4 w0 = Ws4[(k4*4+0)*25 + ocg];
    float4 w1 = Ws4[(k4*4+1)*25 + ocg];
    float4 w2 = Ws4[(k4*4+2)*25 + ocg];
    float4 w3 = Ws4[(k4*4+3)*25 + ocg];
    #pragma unroll
    for (int jj=0;jj<4;jj++){
      float4 xv = Xs4[(r0+jj)*25 + (k4 ^ rowg)];
      fma_row(acc[jj], xv, w0, w1, w2, w3);
    }
  }
}

// Pass 1: per-channel sum/sumsq of y = x @ W^T (no bias; it cancels in BN)
// and (optionally) raw-x segment sums.
template<bool DO_SEG>
__global__ __launch_bounds__(192) void head_stats_kernel(
    const float* __restrict__ X, const float* __restrict__ W,
    float* __restrict__ gsum, float* __restrict__ gsum2, float* __restrict__ gseg)
{
  __shared__ __align__(16) float Ws[9600];
  __shared__ __align__(16) float Xs[3200];
  __shared__ float red[192];
  const int tid = threadIdx.x;
  const int ocg = tid % 24, rowg = tid / 24;
  const int oc0 = ocg*4,  r0  = rowg*4;
  load_W(W, Ws, tid);
  float sY[4]={0,0,0,0}, sY2[4]={0,0,0,0};
  float segc = 0.f;
  const int base = blockIdx.x * 24576;      // 256 rows * 96 ch
  for (int rt=0; rt<8; ++rt){
    __syncthreads();
    stage_rows(X + base + rt*3072, Xs, tid);
    __syncthreads();
    if (DO_SEG && tid < 96){
      #pragma unroll
      for (int r=0;r<32;r++) segc += Xs[r*100 + (tid ^ ((r>>2)<<2))];
    }
    float4 acc[4];
    gemm_tile(Xs, Ws, ocg, rowg, r0, acc);
    #pragma unroll
    for (int jj=0;jj<4;jj++){
      float4 a = acc[jj];
      sY[0]+=a.x; sY2[0]=fmaf(a.x,a.x,sY2[0]);
      sY[1]+=a.y; sY2[1]=fmaf(a.y,a.y,sY2[1]);
      sY[2]+=a.z; sY2[2]=fmaf(a.z,a.z,sY2[2]);
      sY[3]+=a.w; sY2[3]=fmaf(a.w,a.w,sY2[3]);
    }
  }
  red[tid]=0.f;
  __syncthreads();
  #pragma unroll
  for (int i=0;i<4;i++){
    atomicAdd(&red[oc0+i],    sY[i]);
    atomicAdd(&red[96+oc0+i], sY2[i]);
  }
  __syncthreads();
  if (tid<96){
    atomicAdd(gsum+tid,  red[tid]);
    atomicAdd(gsum2+tid, red[96+tid]);
    if (DO_SEG) atomicAdd(gseg + (blockIdx.x>>3)*96 + tid, segc);
  }
}

// BN scale/shift from sums (training-mode batch stats, biased var)
__global__ void bn_params_kernel(const float* __restrict__ gq_gamma, const float* __restrict__ gq_beta,
                                 const float* __restrict__ gk_gamma, const float* __restrict__ gk_beta,
                                 float* __restrict__ ws)
{
  const int t = threadIdx.x;
  const float invN = 1.0f/(float)NPTS;
  if (t < 96){
    float mu  = ws[WS_GQ_SUM+t]*invN;
    float var = ws[WS_GQ_SUM2+t]*invN - mu*mu;
    float sc  = gq_gamma[t]*rsqrtf(var + 1e-5f);
    ws[WS_GQ_SCALE+t] = sc;
    ws[WS_GQ_SHIFT+t] = gq_beta[t] - mu*sc;
  } else if (t < 192){
    int c = t-96;
    float mu  = ws[WS_GK_SUM+c]*invN;
    float var = ws[WS_GK_SUM2+c]*invN - mu*mu;
    float sc  = gk_gamma[c]*rsqrtf(var + 1e-5f);
    ws[WS_GK_SCALE+c] = sc;
    ws[WS_GK_SHIFT+c] = gk_beta[c] - mu*sc;
  }
}

// Pass 2 over view2: relu(BN(y)) segment sums
__global__ __launch_bounds__(192) void head_apply_kernel(
    const float* __restrict__ X, const float* __restrict__ W,
    const float* __restrict__ scale, const float* __restrict__ shift,
    float* __restrict__ gseg)
{
  __shared__ __align__(16) float Ws[9600];
  __shared__ __align__(16) float Xs[3200];
  __shared__ float red[96];
  const int tid = threadIdx.x;
  const int ocg = tid % 24, rowg = tid / 24;
  const int oc0 = ocg*4,  r0  = rowg*4;
  load_W(W, Ws, tid);
  float4 sc = make_float4(scale[oc0],scale[oc0+1],scale[oc0+2],scale[oc0+3]);
  float4 sh = make_float4(shift[oc0],shift[oc0+1],shift[oc0+2],shift[oc0+3]);
  float4 gs = make_float4(0.f,0.f,0.f,0.f);
  const int base = blockIdx.x * 24576;
  for (int rt=0; rt<8; ++rt){
    __syncthreads();
    stage_rows(X + base + rt*3072, Xs, tid);
    __syncthreads();
    float4 acc[4];
    gemm_tile(Xs, Ws, ocg, rowg, r0, acc);
    #pragma unroll
    for (int jj=0;jj<4;jj++){
      gs.x += fmaxf(fmaf(acc[jj].x,sc.x,sh.x),0.f);
      gs.y += fmaxf(fmaf(acc[jj].y,sc.y,sh.y),0.f);
      gs.z += fmaxf(fmaf(acc[jj].z,sc.z,sh.z),0.f);
      gs.w += fmaxf(fmaf(acc[jj].w,sc.w,sh.w),0.f);
    }
  }
  if (tid<96) red[tid]=0.f;
  __syncthreads();
  atomicAdd(&red[oc0+0], gs.x);
  atomicAdd(&red[oc0+1], gs.y);
  atomicAdd(&red[oc0+2], gs.z);
  atomicAdd(&red[oc0+3], gs.w);
  __syncthreads();
  if (tid<96) atomicAdd(gseg + (blockIdx.x>>3)*96 + tid, red[tid]);
}

// anchor = l2norm(segsum/2048)
__global__ __launch_bounds__(128) void anchor_kernel(
    const float* __restrict__ segsum, float* __restrict__ dst)
{
  __shared__ float red[128];
  const int t = threadIdx.x, s = blockIdx.x;
  float m = 0.f;
  if (t<96) m = segsum[s*96+t] * (1.0f/2048.0f);
  red[t] = m*m;
  __syncthreads();
  for (int off=64; off>0; off>>=1){
    if (t<off) red[t]+=red[t+off];
    __syncthreads();
  }
  float inv = 1.0f/(sqrtf(red[0]) + 1e-7f);
  if (t<96) dst[s*96+t] = m*inv;
}

// gather 32 sampled view1 rows -> raw l2norm (samples^T) + gk-head l2norm (samples2^T)
__global__ __launch_bounds__(192) void samples_kernel(
    const float* __restrict__ V1, const float* __restrict__ W,
    const float* __restrict__ scale, const float* __restrict__ shift,
    const int* __restrict__ idxs,
    float* __restrict__ sampT, float* __restrict__ samp2T)
{
  __shared__ __align__(16) float Ws[9600];
  __shared__ __align__(16) float Xs[3200];
  __shared__ __align__(16) float Gs[3200];
  __shared__ float invr[32], invh[32];
  const int tid = threadIdx.x;
  const int ocg = tid % 24, rowg = tid / 24;
  const int oc0 = ocg*4,  r0  = rowg*4;
  load_W(W, Ws, tid);
  const int base = blockIdx.x * 32;
  #pragma unroll
  for (int i=0;i<4;i++){
    int f = i*768 + tid*4;
    int row = f/96, col = f%96;
    int g = idxs[base+row];
    float4 v = *reinterpret_cast<const float4*>(V1 + g*96 + col);
    *reinterpret_cast<float4*>(Xs + row*100 + (col ^ ((row>>2)<<2))) = v;
  }
  __syncthreads();
  if (tid<32){
    float s=0.f;
    #pragma unroll
    for (int k=0;k<96;k++){ float v=Xs[tid*100+(k^((tid>>2)<<2))]; s=fmaf(v,v,s); }
    invr[tid]=1.0f/(sqrtf(s)+1e-7f);
  }
  __syncthreads();
  {
    int rr=tid&31, kg=tid>>5;
    float inv=invr[rr];
    #pragma unroll
    for (int kk=0;kk<16;kk++){
      int k=kg*16+kk;
      sampT[k*SK + base + rr] = Xs[rr*100 + (k ^ ((rr>>2)<<2))]*inv;
    }
  }
  float4 acc[4];
  gemm_tile(Xs, Ws, ocg, rowg, r0, acc);
  float4 sc = make_float4(scale[oc0],scale[oc0+1],scale[oc0+2],scale[oc0+3]);
  float4 sh = make_float4(shift[oc0],shift[oc0+1],shift[oc0+2],shift[oc0+3]);
  #pragma unroll
  for (int jj=0;jj<4;jj++){
    int rr=r0+jj;
    float4 g;
    g.x=fmaxf(fmaf(acc[jj].x,sc.x,sh.x),0.f);
    g.y=fmaxf(fmaf(acc[jj].y,sc.y,sh.y),0.f);
    g.z=fmaxf(fmaf(acc[jj].z,sc.z,sh.z),0.f);
    g.w=fmaxf(fmaf(acc[jj].w,sc.w,sh.w),0.f);
    *reinterpret_cast<float4*>(Gs + rr*100 + (oc0 ^ ((rr>>2)<<2))) = g;
  }
  __syncthreads();
  if (tid<32){
    float s=0.f;
    #pragma unroll
    for (int k=0;k<96;k++){ float v=Gs[tid*100+(k^((tid>>2)<<2))]; s=fmaf(v,v,s); }
    invh[tid]=1.0f/(sqrtf(s)+1e-7f);
  }
  __syncthreads();
  {
    int rr=tid&31, kg=tid>>5;
    float inv=invh[rr];
    #pragma unroll
    for (int kk=0;kk<16;kk++){
      int k=kg*16+kk;
      samp2T[k*SK + base + rr] = Gs[rr*100 + (k ^ ((rr>>2)<<2))]*inv;
    }
  }
}

// Lcon: 60 relevant columns per row (30 diag positives + 30 linspace negatives)
__global__ __launch_bounds__(64) void lcon1_kernel(
    const float* __restrict__ anchor, const float* __restrict__ sampT, float* __restrict__ out)
{
  __shared__ float a[96];
  const int tid = threadIdx.x, r = blockIdx.x;
  for (int i=tid;i<96;i+=64) a[i]=anchor[r*96+i];
  __syncthreads();
  int c = 0;
  if (tid<30) c = r*30+tid;
  else if (tid<60){
    int j = tid-30;
    int p = (int)((double)j * 7649.0 / 29.0);   // linspace(0, M-1, 30).astype(int32)
    c = (p < r*30) ? p : p+30;                  // skip own block
  }
  float s=0.f;
  if (tid<60){
    for (int k=0;k<96;k++) s = fmaf(a[k], sampT[k*SK+c], s);
  }
  float logit = 2.0f*s;                          // /T, T=0.5
  float se = (tid<60) ? expf(logit) : 0.f;
  float sp = (tid<30) ? logit : 0.f;
  #pragma unroll
  for (int off=32; off; off>>=1){ se += __shfl_xor(se,off); sp += __shfl_xor(sp,off); }
  if (tid==0){
    float row = sp*(1.0f/30.0f) - logf(se);
    atomicAdd(out, -row*(1.0f/256.0f));
  }
}

// Lcon2: full sim2 row, top-30 positives, bg-split negatives
__global__ __launch_bounds__(256) void lcon2_kernel(
    const float* __restrict__ anchor2, const float* __restrict__ samp2T,
    const int* __restrict__ bg, float* __restrict__ out)
{
  __shared__ float a[96];
  __shared__ float srow[SK];
  __shared__ float wvv[4];
  __shared__ int   wcc[4];
  __shared__ int   winc_s;
  __shared__ int   sel[30];
  const int tid = threadIdx.x, r = blockIdx.x;
  const int lane = tid & 63, wid = tid >> 6;
  if (tid<96) a[tid]=anchor2[r*96+tid];
  __syncthreads();
  float val[30];
  #pragma unroll
  for (int j=0;j<30;j++){
    int c = tid + (j<<8);
    float s=0.f;
    for (int k=0;k<96;k++) s = fmaf(a[k], samp2T[k*SK+c], s);
    val[j]=s; srow[c]=s;
  }
  __syncthreads();
  unsigned mask=0; float possum=0.f;
  for (int it=0; it<30; ++it){
    float bv = -3.0e38f; int bc = 1<<30;
    #pragma unroll
    for (int j=0;j<30;j++){
      if (!((mask>>j)&1u)){
        float v = val[j]; int c = tid + (j<<8);
        if (v > bv || (v == bv && c < bc)){ bv=v; bc=c; }
      }
    }
    #pragma unroll
    for (int off=32; off; off>>=1){
      float ov = __shfl_xor(bv, off); int ocx = __shfl_xor(bc, off);
      if (ov > bv || (ov == bv && ocx < bc)){ bv=ov; bc=ocx; }
    }
    if (lane==0){ wvv[wid]=bv; wcc[wid]=bc; }
    __syncthreads();
    if (tid==0){
      float v=wvv[0]; int c=wcc[0];
      #pragma unroll
      for (int w=1;w<4;w++){
        if (wvv[w]>v || (wvv[w]==v && wcc[w]<c)){ v=wvv[w]; c=wcc[w]; }
      }
      winc_s=c; sel[it]=c; possum += v;
    }
    __syncthreads();
    int c = winc_s;
    if ((c & 255) == tid) mask |= 1u << (c >> 8);
  }
  // negatives: bg-split, excluding own block
  const int bgr = bg[r];
  float se=0.f;
  #pragma unroll
  for (int j=0;j<30;j++){
    int c = tid + (j<<8);
    int seg = c/30;
    int bgc = bg[seg];
    bool nf = ((bgr!=0) ? (bgc==0) : (bgc!=0)) && (seg != r);
    if (nf) se += expf(2.0f*val[j]);
  }
  #pragma unroll
  for (int off=32; off; off>>=1) se += __shfl_xor(se, off);
  if (lane==0) wvv[wid]=se;
  __syncthreads();
  float ex=0.f;
  if (tid<30){
    int c = sel[tid]; int seg=c/30; int bgc=bg[seg];
    bool nf = ((bgr!=0) ? (bgc==0) : (bgc!=0)) && (seg != r);
    if (!nf) ex = expf(2.0f*srow[c]);        // positive not already in denom via neg
  }
  if (wid==0){
    #pragma unroll
    for (int off=32; off; off>>=1) ex += __shfl_xor(ex, off);
  }
  if (tid==0){
    float lse = logf(wvv[0]+wvv[1]+wvv[2]+wvv[3] + ex);
    float row = possum*(2.0f/30.0f) - lse;
    atomicAdd(out, -row*(1.0f/256.0f));
  }
}

extern "C" void kernel_launch(void* const* d_in, const int* in_sizes, int n_in,
                              void* d_out, int out_size, void* d_ws, size_t ws_size,
                              hipStream_t stream) {
  (void)in_sizes; (void)n_in; (void)out_size; (void)ws_size;
  const float* v1       = (const float*)d_in[0];
  const float* v2       = (const float*)d_in[1];
  const float* gq_w     = (const float*)d_in[2];
  const float* gq_gamma = (const float*)d_in[4];
  const float* gq_beta  = (const float*)d_in[5];
  const float* gk_w     = (const float*)d_in[6];
  const float* gk_gamma = (const float*)d_in[8];
  const float* gk_beta  = (const float*)d_in[9];
  const int*   idxs     = (const int*)d_in[12];
  const int*   bg       = (const int*)d_in[13];
  float* ws  = (float*)d_ws;
  float* out = (float*)d_out;

  hipMemsetAsync(ws, 0, (size_t)WS_ANCHOR1*sizeof(float), stream);  // sums + segsums
  hipMemsetAsync(out, 0, sizeof(float), stream);

  head_stats_kernel<true ><<<2048,192,0,stream>>>(v2, gq_w, ws+WS_GQ_SUM, ws+WS_GQ_SUM2, ws+WS_SEGX2);
  head_stats_kernel<false><<<2048,192,0,stream>>>(v1, gk_w, ws+WS_GK_SUM, ws+WS_GK_SUM2, nullptr);
  bn_params_kernel<<<1,192,0,stream>>>(gq_gamma, gq_beta, gk_gamma, gk_beta, ws);
  anchor_kernel<<<256,128,0,stream>>>(ws+WS_SEGX2, ws+WS_ANCHOR1);
  head_apply_kernel<<<2048,192,0,stream>>>(v2, gq_w, ws+WS_GQ_SCALE, ws+WS_GQ_SHIFT, ws+WS_SEGG2);
  anchor_kernel<<<256,128,0,stream>>>(ws+WS_SEGG2, ws+WS_ANCHOR2);
  samples_kernel<<<240,192,0,stream>>>(v1, gk_w, ws+WS_GK_SCALE, ws+WS_GK_SHIFT, idxs,
                                       ws+WS_SAMPT, ws+WS_SAMP2T);
  lcon1_kernel<<<256,64,0,stream>>>(ws+WS_ANCHOR1, ws+WS_SAMPT, out);
  lcon2_kernel<<<256,256,0,stream>>>(ws+WS_ANCHOR2, ws+WS_SAMP2T, bg, out);
}

// Round 2
// 1299.002 us; speedup vs baseline: 1.3237x; 1.3237x over previous
//
#include <hip/hip_runtime.h>
#include <math.h>

#define SK 7680          // 256 segments * 30 samples
#define NPTS 524288

// ---- workspace float offsets ----
#define WS_GQ_SUM   0
#define WS_GQ_SUM2  96
#define WS_GK_SUM   192
#define WS_GK_SUM2  288
#define WS_GQ_SCALE 384
#define WS_GQ_SHIFT 480
#define WS_GK_SCALE 576
#define WS_GK_SHIFT 672
#define WS_SEGX2    768                 // 256*96 raw view2 segment sums
#define WS_SEGG2    25344               // 256*96 head(view2) segment sums
#define WS_ANCHOR1  49920               // 256*96
#define WS_ANCHOR2  74496               // 256*96
#define WS_SAMPT    99072               // [96][7680] raw samples^T
#define WS_SAMP2T   836352              // [96][7680] head samples^T
// total = 1573632 floats = 6.0 MB

__device__ __forceinline__ void fma_row(float4& acc, const float4 x,
    const float4 w0, const float4 w1, const float4 w2, const float4 w3){
  acc.x = fmaf(x.x,w0.x, fmaf(x.y,w1.x, fmaf(x.z,w2.x, fmaf(x.w,w3.x, acc.x))));
  acc.y = fmaf(x.x,w0.y, fmaf(x.y,w1.y, fmaf(x.z,w2.y, fmaf(x.w,w3.y, acc.y))));
  acc.z = fmaf(x.x,w0.z, fmaf(x.y,w1.z, fmaf(x.z,w2.z, fmaf(x.w,w3.z, acc.z))));
  acc.w = fmaf(x.x,w0.w, fmaf(x.y,w1.w, fmaf(x.z,w2.w, fmaf(x.w,w3.w, acc.w))));
}

// W (96x96, row-major W[oc][k]) -> LDS transposed Ws[k*100+oc]
__device__ __forceinline__ void load_W(const float* __restrict__ W, float* Ws, int tid){
  #pragma unroll
  for (int i=0;i<12;i++){
    int f = i*768 + tid*4;            // 192 threads * 4 floats
    int oc = f/96, k = f%96;
    float4 w4 = *reinterpret_cast<const float4*>(W + f);
    Ws[(k+0)*100+oc]=w4.x; Ws[(k+1)*100+oc]=w4.y;
    Ws[(k+2)*100+oc]=w4.z; Ws[(k+3)*100+oc]=w4.w;
  }
}

// stage 32 contiguous rows (32*96 floats) into swizzled LDS tile Xs[32][100]
__device__ __forceinline__ void stage_rows(const float* __restrict__ src, float* Xs, int tid){
  #pragma unroll
  for (int i=0;i<4;i++){
    int f = i*768 + tid*4;
    int row = f/96, col = f%96;
    float4 v = *reinterpret_cast<const float4*>(src + f);
    *reinterpret_cast<float4*>(Xs + row*100 + (col ^ ((row>>2)<<2))) = v;
  }
}

// one 32-row x 96-oc tile: per-thread 4 rows x 4 ocs
__device__ __forceinline__ void gemm_tile(const float* Xs, const float* Ws,
    int ocg, int rowg, int r0, float4 acc[4]){
  const float4* Xs4 = reinterpret_cast<const float4*>(Xs);
  const float4* Ws4 = reinterpret_cast<const float4*>(Ws);
  acc[0]=acc[1]=acc[2]=acc[3]=make_float4(0.f,0.f,0.f,0.f);
  #pragma unroll 4
  for (int k4=0;k4<24;k4++){
    float4 w0 = Ws4[(k4*4+0)*25 + ocg];
    float4 w1 = Ws4[(k4*4+1)*25 + ocg];
    float4 w2 = Ws4[(k4*4+2)*25 + ocg];
    float4 w3 = Ws4[(k4*4+3)*25 + ocg];
    #pragma unroll
    for (int jj=0;jj<4;jj++){
      float4 xv = Xs4[(r0+jj)*25 + (k4 ^ rowg)];
      fma_row(acc[jj], xv, w0, w1, w2, w3);
    }
  }
}

// Pass 1: per-channel sum/sumsq of y = x @ W^T (no bias; it cancels in BN)
// and (optionally) raw-x segment sums.
template<bool DO_SEG>
__global__ __launch_bounds__(192) void head_stats_kernel(
    const float* __restrict__ X, const float* __restrict__ W,
    float* __restrict__ gsum, float* __restrict__ gsum2, float* __restrict__ gseg)
{
  __shared__ __align__(16) float Ws[9600];
  __shared__ __align__(16) float Xs[3200];
  __shared__ float red[192];
  const int tid = threadIdx.x;
  const int ocg = tid % 24, rowg = tid / 24;
  const int oc0 = ocg*4,  r0  = rowg*4;
  load_W(W, Ws, tid);
  float sY[4]={0,0,0,0}, sY2[4]={0,0,0,0};
  float segc = 0.f;
  const int base = blockIdx.x * 24576;      // 256 rows * 96 ch
  for (int rt=0; rt<8; ++rt){
    __syncthreads();
    stage_rows(X + base + rt*3072, Xs, tid);
    __syncthreads();
    if (DO_SEG && tid < 96){
      #pragma unroll
      for (int r=0;r<32;r++) segc += Xs[r*100 + (tid ^ ((r>>2)<<2))];
    }
    float4 acc[4];
    gemm_tile(Xs, Ws, ocg, rowg, r0, acc);
    #pragma unroll
    for (int jj=0;jj<4;jj++){
      float4 a = acc[jj];
      sY[0]+=a.x; sY2[0]=fmaf(a.x,a.x,sY2[0]);
      sY[1]+=a.y; sY2[1]=fmaf(a.y,a.y,sY2[1]);
      sY[2]+=a.z; sY2[2]=fmaf(a.z,a.z,sY2[2]);
      sY[3]+=a.w; sY2[3]=fmaf(a.w,a.w,sY2[3]);
    }
  }
  red[tid]=0.f;
  __syncthreads();
  #pragma unroll
  for (int i=0;i<4;i++){
    atomicAdd(&red[oc0+i],    sY[i]);
    atomicAdd(&red[96+oc0+i], sY2[i]);
  }
  __syncthreads();
  if (tid<96){
    atomicAdd(gsum+tid,  red[tid]);
    atomicAdd(gsum2+tid, red[96+tid]);
    if (DO_SEG) atomicAdd(gseg + (blockIdx.x>>3)*96 + tid, segc);
  }
}

// BN scale/shift from sums (training-mode batch stats, biased var)
__global__ void bn_params_kernel(const float* __restrict__ gq_gamma, const float* __restrict__ gq_beta,
                                 const float* __restrict__ gk_gamma, const float* __restrict__ gk_beta,
                                 float* __restrict__ ws)
{
  const int t = threadIdx.x;
  const float invN = 1.0f/(float)NPTS;
  if (t < 96){
    float mu  = ws[WS_GQ_SUM+t]*invN;
    float var = ws[WS_GQ_SUM2+t]*invN - mu*mu;
    float sc  = gq_gamma[t]*rsqrtf(var + 1e-5f);
    ws[WS_GQ_SCALE+t] = sc;
    ws[WS_GQ_SHIFT+t] = gq_beta[t] - mu*sc;
  } else if (t < 192){
    int c = t-96;
    float mu  = ws[WS_GK_SUM+c]*invN;
    float var = ws[WS_GK_SUM2+c]*invN - mu*mu;
    float sc  = gk_gamma[c]*rsqrtf(var + 1e-5f);
    ws[WS_GK_SCALE+c] = sc;
    ws[WS_GK_SHIFT+c] = gk_beta[c] - mu*sc;
  }
}

// Pass 2 over view2: relu(BN(y)) segment sums
__global__ __launch_bounds__(192) void head_apply_kernel(
    const float* __restrict__ X, const float* __restrict__ W,
    const float* __restrict__ scale, const float* __restrict__ shift,
    float* __restrict__ gseg)
{
  __shared__ __align__(16) float Ws[9600];
  __shared__ __align__(16) float Xs[3200];
  __shared__ float red[96];
  const int tid = threadIdx.x;
  const int ocg = tid % 24, rowg = tid / 24;
  const int oc0 = ocg*4,  r0  = rowg*4;
  load_W(W, Ws, tid);
  float4 sc = make_float4(scale[oc0],scale[oc0+1],scale[oc0+2],scale[oc0+3]);
  float4 sh = make_float4(shift[oc0],shift[oc0+1],shift[oc0+2],shift[oc0+3]);
  float4 gs = make_float4(0.f,0.f,0.f,0.f);
  const int base = blockIdx.x * 24576;
  for (int rt=0; rt<8; ++rt){
    __syncthreads();
    stage_rows(X + base + rt*3072, Xs, tid);
    __syncthreads();
    float4 acc[4];
    gemm_tile(Xs, Ws, ocg, rowg, r0, acc);
    #pragma unroll
    for (int jj=0;jj<4;jj++){
      gs.x += fmaxf(fmaf(acc[jj].x,sc.x,sh.x),0.f);
      gs.y += fmaxf(fmaf(acc[jj].y,sc.y,sh.y),0.f);
      gs.z += fmaxf(fmaf(acc[jj].z,sc.z,sh.z),0.f);
      gs.w += fmaxf(fmaf(acc[jj].w,sc.w,sh.w),0.f);
    }
  }
  if (tid<96) red[tid]=0.f;
  __syncthreads();
  atomicAdd(&red[oc0+0], gs.x);
  atomicAdd(&red[oc0+1], gs.y);
  atomicAdd(&red[oc0+2], gs.z);
  atomicAdd(&red[oc0+3], gs.w);
  __syncthreads();
  if (tid<96) atomicAdd(gseg + (blockIdx.x>>3)*96 + tid, red[tid]);
}

// anchor = l2norm(segsum/2048)
__global__ __launch_bounds__(128) void anchor_kernel(
    const float* __restrict__ segsum, float* __restrict__ dst)
{
  __shared__ float red[128];
  const int t = threadIdx.x, s = blockIdx.x;
  float m = 0.f;
  if (t<96) m = segsum[s*96+t] * (1.0f/2048.0f);
  red[t] = m*m;
  __syncthreads();
  for (int off=64; off>0; off>>=1){
    if (t<off) red[t]+=red[t+off];
    __syncthreads();
  }
  float inv = 1.0f/(sqrtf(red[0]) + 1e-7f);
  if (t<96) dst[s*96+t] = m*inv;
}

// gather 32 sampled view1 rows -> raw l2norm (samples^T) + gk-head l2norm (samples2^T)
__global__ __launch_bounds__(192) void samples_kernel(
    const float* __restrict__ V1, const float* __restrict__ W,
    const float* __restrict__ scale, const float* __restrict__ shift,
    const int* __restrict__ idxs,
    float* __restrict__ sampT, float* __restrict__ samp2T)
{
  __shared__ __align__(16) float Ws[9600];
  __shared__ __align__(16) float Xs[3200];
  __shared__ __align__(16) float Gs[3200];
  __shared__ float invr[32], invh[32];
  const int tid = threadIdx.x;
  const int ocg = tid % 24, rowg = tid / 24;
  const int oc0 = ocg*4,  r0  = rowg*4;
  load_W(W, Ws, tid);
  const int base = blockIdx.x * 32;
  #pragma unroll
  for (int i=0;i<4;i++){
    int f = i*768 + tid*4;
    int row = f/96, col = f%96;
    int g = idxs[base+row];
    float4 v = *reinterpret_cast<const float4*>(V1 + g*96 + col);
    *reinterpret_cast<float4*>(Xs + row*100 + (col ^ ((row>>2)<<2))) = v;
  }
  __syncthreads();
  if (tid<32){
    float s=0.f;
    #pragma unroll
    for (int k=0;k<96;k++){ float v=Xs[tid*100+(k^((tid>>2)<<2))]; s=fmaf(v,v,s); }
    invr[tid]=1.0f/(sqrtf(s)+1e-7f);
  }
  __syncthreads();
  {
    int rr=tid&31, kg=tid>>5;
    float inv=invr[rr];
    #pragma unroll
    for (int kk=0;kk<16;kk++){
      int k=kg*16+kk;
      sampT[k*SK + base + rr] = Xs[rr*100 + (k ^ ((rr>>2)<<2))]*inv;
    }
  }
  float4 acc[4];
  gemm_tile(Xs, Ws, ocg, rowg, r0, acc);
  float4 sc = make_float4(scale[oc0],scale[oc0+1],scale[oc0+2],scale[oc0+3]);
  float4 sh = make_float4(shift[oc0],shift[oc0+1],shift[oc0+2],shift[oc0+3]);
  #pragma unroll
  for (int jj=0;jj<4;jj++){
    int rr=r0+jj;
    float4 g;
    g.x=fmaxf(fmaf(acc[jj].x,sc.x,sh.x),0.f);
    g.y=fmaxf(fmaf(acc[jj].y,sc.y,sh.y),0.f);
    g.z=fmaxf(fmaf(acc[jj].z,sc.z,sh.z),0.f);
    g.w=fmaxf(fmaf(acc[jj].w,sc.w,sh.w),0.f);
    *reinterpret_cast<float4*>(Gs + rr*100 + (oc0 ^ ((rr>>2)<<2))) = g;
  }
  __syncthreads();
  if (tid<32){
    float s=0.f;
    #pragma unroll
    for (int k=0;k<96;k++){ float v=Gs[tid*100+(k^((tid>>2)<<2))]; s=fmaf(v,v,s); }
    invh[tid]=1.0f/(sqrtf(s)+1e-7f);
  }
  __syncthreads();
  {
    int rr=tid&31, kg=tid>>5;
    float inv=invh[rr];
    #pragma unroll
    for (int kk=0;kk<16;kk++){
      int k=kg*16+kk;
      samp2T[k*SK + base + rr] = Gs[rr*100 + (k ^ ((rr>>2)<<2))]*inv;
    }
  }
}

// Lcon: 60 relevant columns per row (30 diag positives + 30 linspace negatives)
__global__ __launch_bounds__(64) void lcon1_kernel(
    const float* __restrict__ anchor, const float* __restrict__ sampT, float* __restrict__ out)
{
  __shared__ float a[96];
  const int tid = threadIdx.x, r = blockIdx.x;
  for (int i=tid;i<96;i+=64) a[i]=anchor[r*96+i];
  __syncthreads();
  int c = 0;
  if (tid<30) c = r*30+tid;
  else if (tid<60){
    int j = tid-30;
    int p = (int)((double)j * 7649.0 / 29.0);   // linspace(0, M-1, 30).astype(int32)
    c = (p < r*30) ? p : p+30;                  // skip own block
  }
  float s=0.f;
  if (tid<60){
    #pragma unroll
    for (int k=0;k<96;k++) s = fmaf(a[k], sampT[k*SK+c], s);
  }
  float logit = 2.0f*s;                          // /T, T=0.5
  float se = (tid<60) ? expf(logit) : 0.f;
  float sp = (tid<30) ? logit : 0.f;
  #pragma unroll
  for (int off=32; off; off>>=1){ se += __shfl_xor(se,off); sp += __shfl_xor(sp,off); }
  if (tid==0){
    float row = sp*(1.0f/30.0f) - logf(se);
    atomicAdd(out, -row*(1.0f/256.0f));
  }
}

// Lcon2: full sim2 row, top-30 positives, bg-split negatives
// Dot phase restructured: k OUTER, j=0..29 inner fully unrolled -> 30 independent
// coalesced loads in flight per k-step (software-pipelined), no serial L2-latency chain.
__global__ __launch_bounds__(256) void lcon2_kernel(
    const float* __restrict__ anchor2, const float* __restrict__ samp2T,
    const int* __restrict__ bg, float* __restrict__ out)
{
  __shared__ float a[96];
  __shared__ float srow[SK];
  __shared__ float wvv[4];
  __shared__ int   wcc[4];
  __shared__ int   winc_s;
  __shared__ int   sel[30];
  const int tid = threadIdx.x, r = blockIdx.x;
  const int lane = tid & 63, wid = tid >> 6;
  if (tid<96) a[tid]=anchor2[r*96+tid];
  __syncthreads();
  float val[30];
  #pragma unroll
  for (int j=0;j<30;j++) val[j]=0.f;
  {
    const float* __restrict__ p = samp2T + tid;
    #pragma unroll 4
    for (int k=0;k<96;k++){
      float ak = a[k];
      const float* __restrict__ pk = p + k*SK;
      #pragma unroll
      for (int j=0;j<30;j++) val[j] = fmaf(ak, pk[j<<8], val[j]);
    }
  }
  #pragma unroll
  for (int j=0;j<30;j++) srow[tid + (j<<8)] = val[j];
  __syncthreads();
  unsigned mask=0; float possum=0.f;
  for (int it=0; it<30; ++it){
    float bv = -3.0e38f; int bc = 1<<30;
    #pragma unroll
    for (int j=0;j<30;j++){
      if (!((mask>>j)&1u)){
        float v = val[j]; int c = tid + (j<<8);
        if (v > bv || (v == bv && c < bc)){ bv=v; bc=c; }
      }
    }
    #pragma unroll
    for (int off=32; off; off>>=1){
      float ov = __shfl_xor(bv, off); int ocx = __shfl_xor(bc, off);
      if (ov > bv || (ov == bv && ocx < bc)){ bv=ov; bc=ocx; }
    }
    if (lane==0){ wvv[wid]=bv; wcc[wid]=bc; }
    __syncthreads();
    if (tid==0){
      float v=wvv[0]; int c=wcc[0];
      #pragma unroll
      for (int w=1;w<4;w++){
        if (wvv[w]>v || (wvv[w]==v && wcc[w]<c)){ v=wvv[w]; c=wcc[w]; }
      }
      winc_s=c; sel[it]=c; possum += v;
    }
    __syncthreads();
    int c = winc_s;
    if ((c & 255) == tid) mask |= 1u << (c >> 8);
  }
  // negatives: bg-split, excluding own block
  const int bgr = bg[r];
  float se=0.f;
  #pragma unroll
  for (int j=0;j<30;j++){
    int c = tid + (j<<8);
    int seg = c/30;
    int bgc = bg[seg];
    bool nf = ((bgr!=0) ? (bgc==0) : (bgc!=0)) && (seg != r);
    if (nf) se += expf(2.0f*val[j]);
  }
  #pragma unroll
  for (int off=32; off; off>>=1) se += __shfl_xor(se, off);
  if (lane==0) wvv[wid]=se;
  __syncthreads();
  float ex=0.f;
  if (tid<30){
    int c = sel[tid]; int seg=c/30; int bgc=bg[seg];
    bool nf = ((bgr!=0) ? (bgc==0) : (bgc!=0)) && (seg != r);
    if (!nf) ex = expf(2.0f*srow[c]);        // positive not already in denom via neg
  }
  if (wid==0){
    #pragma unroll
    for (int off=32; off; off>>=1) ex += __shfl_xor(ex, off);
  }
  if (tid==0){
    float lse = logf(wvv[0]+wvv[1]+wvv[2]+wvv[3] + ex);
    float row = possum*(2.0f/30.0f) - lse;
    atomicAdd(out, -row*(1.0f/256.0f));
  }
}

extern "C" void kernel_launch(void* const* d_in, const int* in_sizes, int n_in,
                              void* d_out, int out_size, void* d_ws, size_t ws_size,
                              hipStream_t stream) {
  (void)in_sizes; (void)n_in; (void)out_size; (void)ws_size;
  const float* v1       = (const float*)d_in[0];
  const float* v2       = (const float*)d_in[1];
  const float* gq_w     = (const float*)d_in[2];
  const float* gq_gamma = (const float*)d_in[4];
  const float* gq_beta  = (const float*)d_in[5];
  const float* gk_w     = (const float*)d_in[6];
  const float* gk_gamma = (const float*)d_in[8];
  const float* gk_beta  = (const float*)d_in[9];
  const int*   idxs     = (const int*)d_in[12];
  const int*   bg       = (const int*)d_in[13];
  float* ws  = (float*)d_ws;
  float* out = (float*)d_out;

  hipMemsetAsync(ws, 0, (size_t)WS_ANCHOR1*sizeof(float), stream);  // sums + segsums
  hipMemsetAsync(out, 0, sizeof(float), stream);

  head_stats_kernel<true ><<<2048,192,0,stream>>>(v2, gq_w, ws+WS_GQ_SUM, ws+WS_GQ_SUM2, ws+WS_SEGX2);
  head_stats_kernel<false><<<2048,192,0,stream>>>(v1, gk_w, ws+WS_GK_SUM, ws+WS_GK_SUM2, nullptr);
  bn_params_kernel<<<1,192,0,stream>>>(gq_gamma, gq_beta, gk_gamma, gk_beta, ws);
  anchor_kernel<<<256,128,0,stream>>>(ws+WS_SEGX2, ws+WS_ANCHOR1);
  head_apply_kernel<<<2048,192,0,stream>>>(v2, gq_w, ws+WS_GQ_SCALE, ws+WS_GQ_SHIFT, ws+WS_SEGG2);
  anchor_kernel<<<256,128,0,stream>>>(ws+WS_SEGG2, ws+WS_ANCHOR2);
  samples_kernel<<<240,192,0,stream>>>(v1, gk_w, ws+WS_GK_SCALE, ws+WS_GK_SHIFT, idxs,
                                       ws+WS_SAMPT, ws+WS_SAMP2T);
  lcon1_kernel<<<256,64,0,stream>>>(ws+WS_ANCHOR1, ws+WS_SAMPT, out);
  lcon2_kernel<<<256,256,0,stream>>>(ws+WS_ANCHOR2, ws+WS_SAMP2T, bg, out);
}

// Round 3
// 660.339 us; speedup vs baseline: 2.6040x; 1.9672x over previous
//
#include <hip/hip_runtime.h>
#include <math.h>

#define SK 7680          // 256 segments * 30 samples
#define NPTS 524288

// ---- workspace float offsets ----
#define WS_GQ_SUM   0
#define WS_GQ_SUM2  96
#define WS_GK_SUM   192
#define WS_GK_SUM2  288
#define WS_GQ_SCALE 384
#define WS_GQ_SHIFT 480
#define WS_GK_SCALE 576
#define WS_GK_SHIFT 672
#define WS_SEGX2    768                 // 256*96 raw view2 segment sums
#define WS_SEGG2    25344               // 256*96 head(view2) segment sums
#define WS_ANCHOR1  49920               // 256*96
#define WS_ANCHOR2  74496               // 256*96
#define WS_SAMPT    99072               // [96][7680] raw samples^T
#define WS_SAMP2T   836352              // [96][7680] head samples^T

typedef __attribute__((ext_vector_type(8))) short bf16x8;
typedef __attribute__((ext_vector_type(4))) float f32x4;

__device__ __forceinline__ ushort f2bf(float f){
  union { float f; unsigned u; } v; v.f = f;
  unsigned r = (v.u + 0x7fffu + ((v.u >> 16) & 1u)) >> 16;   // RNE
  return (ushort)r;
}
__device__ __forceinline__ bf16x8 pack8(float4 a, float4 b){
  bf16x8 r;
  r[0]=(short)f2bf(a.x); r[1]=(short)f2bf(a.y); r[2]=(short)f2bf(a.z); r[3]=(short)f2bf(a.w);
  r[4]=(short)f2bf(b.x); r[5]=(short)f2bf(b.y); r[6]=(short)f2bf(b.z); r[7]=(short)f2bf(b.w);
  return r;
}

// ---- MFMA head pass 1: per-channel sum/sumsq of y = x @ W^T (bias cancels in BN),
// optionally fused raw-x per-segment sums. W lives in register fragments (72 VGPR).
// Block = 256 threads (4 waves), 256 rows; grid 2048.
template<bool DO_SEG>
__global__ __launch_bounds__(256) void head_stats_mfma(
    const float* __restrict__ X, const float* __restrict__ W,
    float* __restrict__ gsum, float* __restrict__ gsum2, float* __restrict__ gseg)
{
  const int tid = threadIdx.x;
  const int l = tid & 63, w = tid >> 6;
  const int g = l >> 4, lr = l & 15;

  // B fragments: wf[kt][ot]; lane l supplies W[oc=ot*16+lr][k = kt*32 + g*8 + j]
  bf16x8 wf[3][6];
  #pragma unroll
  for (int ot=0; ot<6; ++ot){
    const float* wr = W + (ot*16+lr)*96 + g*8;
    #pragma unroll
    for (int kt=0; kt<3; ++kt){
      float4 w0 = *reinterpret_cast<const float4*>(wr + kt*32);
      float4 w1 = *reinterpret_cast<const float4*>(wr + kt*32 + 4);
      wf[kt][ot] = pack8(w0, w1);
    }
  }

  float sY[6], sY2[6];
  #pragma unroll
  for (int ot=0; ot<6; ++ot){ sY[ot]=0.f; sY2[ot]=0.f; }
  float rs[24];
  if (DO_SEG){
    #pragma unroll
    for (int t=0; t<24; ++t) rs[t]=0.f;
  }

  const long base_row = (long)blockIdx.x*256 + w*16;
  #pragma unroll 1
  for (int it=0; it<4; ++it){
    const float* xr = X + (base_row + it*64 + lr)*96 + g*8;
    float4 x00 = *reinterpret_cast<const float4*>(xr);
    float4 x01 = *reinterpret_cast<const float4*>(xr+4);
    float4 x10 = *reinterpret_cast<const float4*>(xr+32);
    float4 x11 = *reinterpret_cast<const float4*>(xr+36);
    float4 x20 = *reinterpret_cast<const float4*>(xr+64);
    float4 x21 = *reinterpret_cast<const float4*>(xr+68);
    if (DO_SEG){
      rs[0]+=x00.x; rs[1]+=x00.y; rs[2]+=x00.z; rs[3]+=x00.w;
      rs[4]+=x01.x; rs[5]+=x01.y; rs[6]+=x01.z; rs[7]+=x01.w;
      rs[8]+=x10.x; rs[9]+=x10.y; rs[10]+=x10.z; rs[11]+=x10.w;
      rs[12]+=x11.x; rs[13]+=x11.y; rs[14]+=x11.z; rs[15]+=x11.w;
      rs[16]+=x20.x; rs[17]+=x20.y; rs[18]+=x20.z; rs[19]+=x20.w;
      rs[20]+=x21.x; rs[21]+=x21.y; rs[22]+=x21.z; rs[23]+=x21.w;
    }
    bf16x8 a0 = pack8(x00,x01), a1 = pack8(x10,x11), a2 = pack8(x20,x21);
    #pragma unroll
    for (int ot=0; ot<6; ++ot){
      f32x4 acc = {0.f,0.f,0.f,0.f};
      acc = __builtin_amdgcn_mfma_f32_16x16x32_bf16(a0, wf[0][ot], acc, 0,0,0);
      acc = __builtin_amdgcn_mfma_f32_16x16x32_bf16(a1, wf[1][ot], acc, 0,0,0);
      acc = __builtin_amdgcn_mfma_f32_16x16x32_bf16(a2, wf[2][ot], acc, 0,0,0);
      sY[ot] += acc[0]+acc[1]+acc[2]+acc[3];
      sY2[ot] = fmaf(acc[0],acc[0], fmaf(acc[1],acc[1],
                fmaf(acc[2],acc[2], fmaf(acc[3],acc[3], sY2[ot]))));
    }
  }

  __shared__ float red[192];
  __shared__ float rsg[96];
  if (tid < 192) red[tid]=0.f;
  if (DO_SEG && tid < 96) rsg[tid]=0.f;
  __syncthreads();
  #pragma unroll
  for (int ot=0; ot<6; ++ot){
    float s = sY[ot], s2 = sY2[ot];
    s  += __shfl_xor(s,16);  s  += __shfl_xor(s,32);
    s2 += __shfl_xor(s2,16); s2 += __shfl_xor(s2,32);
    if (g==0){
      atomicAdd(&red[ot*16+lr], s);
      atomicAdd(&red[96+ot*16+lr], s2);
    }
  }
  if (DO_SEG){
    #pragma unroll
    for (int t=0; t<24; ++t){
      float s = rs[t];
      s += __shfl_xor(s,1); s += __shfl_xor(s,2);
      s += __shfl_xor(s,4); s += __shfl_xor(s,8);
      if (lr==0){
        int kt = t>>3, j = t&7;
        atomicAdd(&rsg[kt*32 + g*8 + j], s);
      }
    }
  }
  __syncthreads();
  if (tid<96){
    atomicAdd(gsum+tid,  red[tid]);
    atomicAdd(gsum2+tid, red[96+tid]);
    if (DO_SEG) atomicAdd(gseg + (blockIdx.x>>3)*96 + tid, rsg[tid]);
  }
}

// ---- MFMA head pass 2 (view2): relu(BN(y)) per-segment per-channel sums
__global__ __launch_bounds__(256) void head_apply_mfma(
    const float* __restrict__ X, const float* __restrict__ W,
    const float* __restrict__ scale, const float* __restrict__ shift,
    float* __restrict__ gseg)
{
  const int tid = threadIdx.x;
  const int l = tid & 63, w = tid >> 6;
  const int g = l >> 4, lr = l & 15;

  bf16x8 wf[3][6];
  #pragma unroll
  for (int ot=0; ot<6; ++ot){
    const float* wr = W + (ot*16+lr)*96 + g*8;
    #pragma unroll
    for (int kt=0; kt<3; ++kt){
      float4 w0 = *reinterpret_cast<const float4*>(wr + kt*32);
      float4 w1 = *reinterpret_cast<const float4*>(wr + kt*32 + 4);
      wf[kt][ot] = pack8(w0, w1);
    }
  }
  float sc[6], sh[6], zs[6];
  #pragma unroll
  for (int ot=0; ot<6; ++ot){
    sc[ot]=scale[ot*16+lr]; sh[ot]=shift[ot*16+lr]; zs[ot]=0.f;
  }

  const long base_row = (long)blockIdx.x*256 + w*16;
  #pragma unroll 1
  for (int it=0; it<4; ++it){
    const float* xr = X + (base_row + it*64 + lr)*96 + g*8;
    float4 x00 = *reinterpret_cast<const float4*>(xr);
    float4 x01 = *reinterpret_cast<const float4*>(xr+4);
    float4 x10 = *reinterpret_cast<const float4*>(xr+32);
    float4 x11 = *reinterpret_cast<const float4*>(xr+36);
    float4 x20 = *reinterpret_cast<const float4*>(xr+64);
    float4 x21 = *reinterpret_cast<const float4*>(xr+68);
    bf16x8 a0 = pack8(x00,x01), a1 = pack8(x10,x11), a2 = pack8(x20,x21);
    #pragma unroll
    for (int ot=0; ot<6; ++ot){
      f32x4 acc = {0.f,0.f,0.f,0.f};
      acc = __builtin_amdgcn_mfma_f32_16x16x32_bf16(a0, wf[0][ot], acc, 0,0,0);
      acc = __builtin_amdgcn_mfma_f32_16x16x32_bf16(a1, wf[1][ot], acc, 0,0,0);
      acc = __builtin_amdgcn_mfma_f32_16x16x32_bf16(a2, wf[2][ot], acc, 0,0,0);
      zs[ot] += fmaxf(fmaf(acc[0],sc[ot],sh[ot]),0.f)
              + fmaxf(fmaf(acc[1],sc[ot],sh[ot]),0.f)
              + fmaxf(fmaf(acc[2],sc[ot],sh[ot]),0.f)
              + fmaxf(fmaf(acc[3],sc[ot],sh[ot]),0.f);
    }
  }

  __shared__ float red[96];
  if (tid < 96) red[tid]=0.f;
  __syncthreads();
  #pragma unroll
  for (int ot=0; ot<6; ++ot){
    float s = zs[ot];
    s += __shfl_xor(s,16); s += __shfl_xor(s,32);
    if (g==0) atomicAdd(&red[ot*16+lr], s);
  }
  __syncthreads();
  if (tid<96) atomicAdd(gseg + (blockIdx.x>>3)*96 + tid, red[tid]);
}

// BN scale/shift from sums (training-mode batch stats, biased var)
__global__ void bn_params_kernel(const float* __restrict__ gq_gamma, const float* __restrict__ gq_beta,
                                 const float* __restrict__ gk_gamma, const float* __restrict__ gk_beta,
                                 float* __restrict__ ws)
{
  const int t = threadIdx.x;
  const float invN = 1.0f/(float)NPTS;
  if (t < 96){
    float mu  = ws[WS_GQ_SUM+t]*invN;
    float var = ws[WS_GQ_SUM2+t]*invN - mu*mu;
    float sc  = gq_gamma[t]*rsqrtf(var + 1e-5f);
    ws[WS_GQ_SCALE+t] = sc;
    ws[WS_GQ_SHIFT+t] = gq_beta[t] - mu*sc;
  } else if (t < 192){
    int c = t-96;
    float mu  = ws[WS_GK_SUM+c]*invN;
    float var = ws[WS_GK_SUM2+c]*invN - mu*mu;
    float sc  = gk_gamma[c]*rsqrtf(var + 1e-5f);
    ws[WS_GK_SCALE+c] = sc;
    ws[WS_GK_SHIFT+c] = gk_beta[c] - mu*sc;
  }
}

// anchor = l2norm(segsum/2048)
__global__ __launch_bounds__(128) void anchor_kernel(
    const float* __restrict__ segsum, float* __restrict__ dst)
{
  __shared__ float red[128];
  const int t = threadIdx.x, s = blockIdx.x;
  float m = 0.f;
  if (t<96) m = segsum[s*96+t] * (1.0f/2048.0f);
  red[t] = m*m;
  __syncthreads();
  for (int off=64; off>0; off>>=1){
    if (t<off) red[t]+=red[t+off];
    __syncthreads();
  }
  float inv = 1.0f/(sqrtf(red[0]) + 1e-7f);
  if (t<96) dst[s*96+t] = m*inv;
}

// ---- fp32 96x96 tile GEMM helpers (used only by samples_kernel) ----
__device__ __forceinline__ void fma_row(float4& acc, const float4 x,
    const float4 w0, const float4 w1, const float4 w2, const float4 w3){
  acc.x = fmaf(x.x,w0.x, fmaf(x.y,w1.x, fmaf(x.z,w2.x, fmaf(x.w,w3.x, acc.x))));
  acc.y = fmaf(x.x,w0.y, fmaf(x.y,w1.y, fmaf(x.z,w2.y, fmaf(x.w,w3.y, acc.y))));
  acc.z = fmaf(x.x,w0.z, fmaf(x.y,w1.z, fmaf(x.z,w2.z, fmaf(x.w,w3.z, acc.z))));
  acc.w = fmaf(x.x,w0.w, fmaf(x.y,w1.w, fmaf(x.z,w2.w, fmaf(x.w,w3.w, acc.w))));
}
__device__ __forceinline__ void load_W(const float* __restrict__ W, float* Ws, int tid){
  #pragma unroll
  for (int i=0;i<12;i++){
    int f = i*768 + tid*4;
    int oc = f/96, k = f%96;
    float4 w4 = *reinterpret_cast<const float4*>(W + f);
    Ws[(k+0)*100+oc]=w4.x; Ws[(k+1)*100+oc]=w4.y;
    Ws[(k+2)*100+oc]=w4.z; Ws[(k+3)*100+oc]=w4.w;
  }
}
__device__ __forceinline__ void gemm_tile(const float* Xs, const float* Ws,
    int ocg, int rowg, int r0, float4 acc[4]){
  const float4* Xs4 = reinterpret_cast<const float4*>(Xs);
  const float4* Ws4 = reinterpret_cast<const float4*>(Ws);
  acc[0]=acc[1]=acc[2]=acc[3]=make_float4(0.f,0.f,0.f,0.f);
  #pragma unroll 4
  for (int k4=0;k4<24;k4++){
    float4 w0 = Ws4[(k4*4+0)*25 + ocg];
    float4 w1 = Ws4[(k4*4+1)*25 + ocg];
    float4 w2 = Ws4[(k4*4+2)*25 + ocg];
    float4 w3 = Ws4[(k4*4+3)*25 + ocg];
    #pragma unroll
    for (int jj=0;jj<4;jj++){
      float4 xv = Xs4[(r0+jj)*25 + (k4 ^ rowg)];
      fma_row(acc[jj], xv, w0, w1, w2, w3);
    }
  }
}

// gather 32 sampled view1 rows -> raw l2norm (samples^T) + gk-head l2norm (samples2^T)
__global__ __launch_bounds__(192) void samples_kernel(
    const float* __restrict__ V1, const float* __restrict__ W,
    const float* __restrict__ scale, const float* __restrict__ shift,
    const int* __restrict__ idxs,
    float* __restrict__ sampT, float* __restrict__ samp2T)
{
  __shared__ __align__(16) float Ws[9600];
  __shared__ __align__(16) float Xs[3200];
  __shared__ __align__(16) float Gs[3200];
  __shared__ float invr[32], invh[32];
  const int tid = threadIdx.x;
  const int ocg = tid % 24, rowg = tid / 24;
  const int oc0 = ocg*4,  r0  = rowg*4;
  load_W(W, Ws, tid);
  const int base = blockIdx.x * 32;
  #pragma unroll
  for (int i=0;i<4;i++){
    int f = i*768 + tid*4;
    int row = f/96, col = f%96;
    int g = idxs[base+row];
    float4 v = *reinterpret_cast<const float4*>(V1 + g*96 + col);
    *reinterpret_cast<float4*>(Xs + row*100 + (col ^ ((row>>2)<<2))) = v;
  }
  __syncthreads();
  if (tid<32){
    float s=0.f;
    #pragma unroll
    for (int k=0;k<96;k++){ float v=Xs[tid*100+(k^((tid>>2)<<2))]; s=fmaf(v,v,s); }
    invr[tid]=1.0f/(sqrtf(s)+1e-7f);
  }
  __syncthreads();
  {
    int rr=tid&31, kg=tid>>5;
    float inv=invr[rr];
    #pragma unroll
    for (int kk=0;kk<16;kk++){
      int k=kg*16+kk;
      sampT[k*SK + base + rr] = Xs[rr*100 + (k ^ ((rr>>2)<<2))]*inv;
    }
  }
  float4 acc[4];
  gemm_tile(Xs, Ws, ocg, rowg, r0, acc);
  float4 sc = make_float4(scale[oc0],scale[oc0+1],scale[oc0+2],scale[oc0+3]);
  float4 sh = make_float4(shift[oc0],shift[oc0+1],shift[oc0+2],shift[oc0+3]);
  #pragma unroll
  for (int jj=0;jj<4;jj++){
    int rr=r0+jj;
    float4 g;
    g.x=fmaxf(fmaf(acc[jj].x,sc.x,sh.x),0.f);
    g.y=fmaxf(fmaf(acc[jj].y,sc.y,sh.y),0.f);
    g.z=fmaxf(fmaf(acc[jj].z,sc.z,sh.z),0.f);
    g.w=fmaxf(fmaf(acc[jj].w,sc.w,sh.w),0.f);
    *reinterpret_cast<float4*>(Gs + rr*100 + (oc0 ^ ((rr>>2)<<2))) = g;
  }
  __syncthreads();
  if (tid<32){
    float s=0.f;
    #pragma unroll
    for (int k=0;k<96;k++){ float v=Gs[tid*100+(k^((tid>>2)<<2))]; s=fmaf(v,v,s); }
    invh[tid]=1.0f/(sqrtf(s)+1e-7f);
  }
  __syncthreads();
  {
    int rr=tid&31, kg=tid>>5;
    float inv=invh[rr];
    #pragma unroll
    for (int kk=0;kk<16;kk++){
      int k=kg*16+kk;
      samp2T[k*SK + base + rr] = Gs[rr*100 + (k ^ ((rr>>2)<<2))]*inv;
    }
  }
}

// Lcon: 60 relevant columns per row (30 diag positives + 30 linspace negatives)
__global__ __launch_bounds__(64) void lcon1_kernel(
    const float* __restrict__ anchor, const float* __restrict__ sampT, float* __restrict__ out)
{
  __shared__ float a[96];
  const int tid = threadIdx.x, r = blockIdx.x;
  for (int i=tid;i<96;i+=64) a[i]=anchor[r*96+i];
  __syncthreads();
  int c = 0;
  if (tid<30) c = r*30+tid;
  else if (tid<60){
    int j = tid-30;
    int p = (int)((double)j * 7649.0 / 29.0);   // linspace(0, M-1, 30).astype(int32)
    c = (p < r*30) ? p : p+30;                  // skip own block
  }
  float s=0.f;
  if (tid<60){
    #pragma unroll
    for (int k=0;k<96;k++) s = fmaf(a[k], sampT[k*SK+c], s);
  }
  float logit = 2.0f*s;                          // /T, T=0.5
  float se = (tid<60) ? expf(logit) : 0.f;
  float sp = (tid<30) ? logit : 0.f;
  #pragma unroll
  for (int off=32; off; off>>=1){ se += __shfl_xor(se,off); sp += __shfl_xor(sp,off); }
  if (tid==0){
    float row = sp*(1.0f/30.0f) - logf(se);
    atomicAdd(out, -row*(1.0f/256.0f));
  }
}

// Lcon2: full sim2 row, top-30 positives, bg-split negatives
__global__ __launch_bounds__(256) void lcon2_kernel(
    const float* __restrict__ anchor2, const float* __restrict__ samp2T,
    const int* __restrict__ bg, float* __restrict__ out)
{
  __shared__ float a[96];
  __shared__ float srow[SK];
  __shared__ float wvv[4];
  __shared__ int   wcc[4];
  __shared__ int   winc_s;
  __shared__ int   sel[30];
  const int tid = threadIdx.x, r = blockIdx.x;
  const int lane = tid & 63, wid = tid >> 6;
  if (tid<96) a[tid]=anchor2[r*96+tid];
  __syncthreads();
  float val[30];
  #pragma unroll
  for (int j=0;j<30;j++) val[j]=0.f;
  {
    const float* __restrict__ p = samp2T + tid;
    #pragma unroll 4
    for (int k=0;k<96;k++){
      float ak = a[k];
      const float* __restrict__ pk = p + k*SK;
      #pragma unroll
      for (int j=0;j<30;j++) val[j] = fmaf(ak, pk[j<<8], val[j]);
    }
  }
  #pragma unroll
  for (int j=0;j<30;j++) srow[tid + (j<<8)] = val[j];
  __syncthreads();
  unsigned mask=0; float possum=0.f;
  for (int it=0; it<30; ++it){
    float bv = -3.0e38f; int bc = 1<<30;
    #pragma unroll
    for (int j=0;j<30;j++){
      if (!((mask>>j)&1u)){
        float v = val[j]; int c = tid + (j<<8);
        if (v > bv || (v == bv && c < bc)){ bv=v; bc=c; }
      }
    }
    #pragma unroll
    for (int off=32; off; off>>=1){
      float ov = __shfl_xor(bv, off); int ocx = __shfl_xor(bc, off);
      if (ov > bv || (ov == bv && ocx < bc)){ bv=ov; bc=ocx; }
    }
    if (lane==0){ wvv[wid]=bv; wcc[wid]=bc; }
    __syncthreads();
    if (tid==0){
      float v=wvv[0]; int c=wcc[0];
      #pragma unroll
      for (int w=1;w<4;w++){
        if (wvv[w]>v || (wvv[w]==v && wcc[w]<c)){ v=wvv[w]; c=wcc[w]; }
      }
      winc_s=c; sel[it]=c; possum += v;
    }
    __syncthreads();
    int c = winc_s;
    if ((c & 255) == tid) mask |= 1u << (c >> 8);
  }
  const int bgr = bg[r];
  float se=0.f;
  #pragma unroll
  for (int j=0;j<30;j++){
    int c = tid + (j<<8);
    int seg = c/30;
    int bgc = bg[seg];
    bool nf = ((bgr!=0) ? (bgc==0) : (bgc!=0)) && (seg != r);
    if (nf) se += expf(2.0f*val[j]);
  }
  #pragma unroll
  for (int off=32; off; off>>=1) se += __shfl_xor(se, off);
  if (lane==0) wvv[wid]=se;
  __syncthreads();
  float ex=0.f;
  if (tid<30){
    int c = sel[tid]; int seg=c/30; int bgc=bg[seg];
    bool nf = ((bgr!=0) ? (bgc==0) : (bgc!=0)) && (seg != r);
    if (!nf) ex = expf(2.0f*srow[c]);        // positive not already in denom via neg
  }
  if (wid==0){
    #pragma unroll
    for (int off=32; off; off>>=1) ex += __shfl_xor(ex, off);
  }
  if (tid==0){
    float lse = logf(wvv[0]+wvv[1]+wvv[2]+wvv[3] + ex);
    float row = possum*(2.0f/30.0f) - lse;
    atomicAdd(out, -row*(1.0f/256.0f));
  }
}

extern "C" void kernel_launch(void* const* d_in, const int* in_sizes, int n_in,
                              void* d_out, int out_size, void* d_ws, size_t ws_size,
                              hipStream_t stream) {
  (void)in_sizes; (void)n_in; (void)out_size; (void)ws_size;
  const float* v1       = (const float*)d_in[0];
  const float* v2       = (const float*)d_in[1];
  const float* gq_w     = (const float*)d_in[2];
  const float* gq_gamma = (const float*)d_in[4];
  const float* gq_beta  = (const float*)d_in[5];
  const float* gk_w     = (const float*)d_in[6];
  const float* gk_gamma = (const float*)d_in[8];
  const float* gk_beta  = (const float*)d_in[9];
  const int*   idxs     = (const int*)d_in[12];
  const int*   bg       = (const int*)d_in[13];
  float* ws  = (float*)d_ws;
  float* out = (float*)d_out;

  hipMemsetAsync(ws, 0, (size_t)WS_ANCHOR1*sizeof(float), stream);  // sums + segsums
  hipMemsetAsync(out, 0, sizeof(float), stream);

  head_stats_mfma<true ><<<2048,256,0,stream>>>(v2, gq_w, ws+WS_GQ_SUM, ws+WS_GQ_SUM2, ws+WS_SEGX2);
  head_stats_mfma<false><<<2048,256,0,stream>>>(v1, gk_w, ws+WS_GK_SUM, ws+WS_GK_SUM2, nullptr);
  bn_params_kernel<<<1,192,0,stream>>>(gq_gamma, gq_beta, gk_gamma, gk_beta, ws);
  anchor_kernel<<<256,128,0,stream>>>(ws+WS_SEGX2, ws+WS_ANCHOR1);
  head_apply_mfma<<<2048,256,0,stream>>>(v2, gq_w, ws+WS_GQ_SCALE, ws+WS_GQ_SHIFT, ws+WS_SEGG2);
  anchor_kernel<<<256,128,0,stream>>>(ws+WS_SEGG2, ws+WS_ANCHOR2);
  samples_kernel<<<240,192,0,stream>>>(v1, gk_w, ws+WS_GK_SCALE, ws+WS_GK_SHIFT, idxs,
                                       ws+WS_SAMPT, ws+WS_SAMP2T);
  lcon1_kernel<<<256,64,0,stream>>>(ws+WS_ANCHOR1, ws+WS_SAMPT, out);
  lcon2_kernel<<<256,256,0,stream>>>(ws+WS_ANCHOR2, ws+WS_SAMP2T, bg, out);
}

// Round 4
// 376.062 us; speedup vs baseline: 4.5725x; 1.7559x over previous
//
#include <hip/hip_runtime.h>
#include <math.h>

#define SK 7680          // 256 segments * 30 samples
#define NPTS 524288

// ---- workspace float offsets ----
#define WS_GQ_SUM   0
#define WS_GQ_SUM2  96
#define WS_GK_SUM   192
#define WS_GK_SUM2  288
#define WS_GQ_SCALE 384
#define WS_GQ_SHIFT 480
#define WS_GK_SCALE 576
#define WS_GK_SHIFT 672
#define WS_SEGX2    768                 // 256*96 raw view2 segment sums
#define WS_SEGG2    25344               // 256*96 head(view2) segment sums
#define WS_ANCHOR1  49920               // 256*96
#define WS_ANCHOR2  74496               // 256*96
#define WS_SAMPT    99072               // [7680][96] raw l2normed samples (row-major)
#define WS_SAMP2T   836352              // [7680][96] head l2normed samples (row-major)
#define WS_SROW     1573632             // [256][7680] sim2 matrix
// total = 3539712 floats = 14.2 MB

typedef __attribute__((ext_vector_type(8))) short bf16x8;
typedef __attribute__((ext_vector_type(4))) float f32x4;

__device__ __forceinline__ ushort f2bf(float f){
  union { float f; unsigned u; } v; v.f = f;
  unsigned r = (v.u + 0x7fffu + ((v.u >> 16) & 1u)) >> 16;   // RNE
  return (ushort)r;
}
__device__ __forceinline__ bf16x8 pack8(float4 a, float4 b){
  bf16x8 r;
  r[0]=(short)f2bf(a.x); r[1]=(short)f2bf(a.y); r[2]=(short)f2bf(a.z); r[3]=(short)f2bf(a.w);
  r[4]=(short)f2bf(b.x); r[5]=(short)f2bf(b.y); r[6]=(short)f2bf(b.z); r[7]=(short)f2bf(b.w);
  return r;
}

// ---- MFMA head pass 1: per-channel sum/sumsq of y = x @ W^T (bias cancels in BN),
// optionally fused raw-x per-segment sums.
template<bool DO_SEG>
__global__ __launch_bounds__(256) void head_stats_mfma(
    const float* __restrict__ X, const float* __restrict__ W,
    float* __restrict__ gsum, float* __restrict__ gsum2, float* __restrict__ gseg)
{
  const int tid = threadIdx.x;
  const int l = tid & 63, w = tid >> 6;
  const int g = l >> 4, lr = l & 15;

  bf16x8 wf[3][6];
  #pragma unroll
  for (int ot=0; ot<6; ++ot){
    const float* wr = W + (ot*16+lr)*96 + g*8;
    #pragma unroll
    for (int kt=0; kt<3; ++kt){
      float4 w0 = *reinterpret_cast<const float4*>(wr + kt*32);
      float4 w1 = *reinterpret_cast<const float4*>(wr + kt*32 + 4);
      wf[kt][ot] = pack8(w0, w1);
    }
  }

  float sY[6], sY2[6];
  #pragma unroll
  for (int ot=0; ot<6; ++ot){ sY[ot]=0.f; sY2[ot]=0.f; }
  float rs[24];
  if (DO_SEG){
    #pragma unroll
    for (int t=0; t<24; ++t) rs[t]=0.f;
  }

  const long base_row = (long)blockIdx.x*256 + w*16;
  #pragma unroll 1
  for (int it=0; it<4; ++it){
    const float* xr = X + (base_row + it*64 + lr)*96 + g*8;
    float4 x00 = *reinterpret_cast<const float4*>(xr);
    float4 x01 = *reinterpret_cast<const float4*>(xr+4);
    float4 x10 = *reinterpret_cast<const float4*>(xr+32);
    float4 x11 = *reinterpret_cast<const float4*>(xr+36);
    float4 x20 = *reinterpret_cast<const float4*>(xr+64);
    float4 x21 = *reinterpret_cast<const float4*>(xr+68);
    if (DO_SEG){
      rs[0]+=x00.x; rs[1]+=x00.y; rs[2]+=x00.z; rs[3]+=x00.w;
      rs[4]+=x01.x; rs[5]+=x01.y; rs[6]+=x01.z; rs[7]+=x01.w;
      rs[8]+=x10.x; rs[9]+=x10.y; rs[10]+=x10.z; rs[11]+=x10.w;
      rs[12]+=x11.x; rs[13]+=x11.y; rs[14]+=x11.z; rs[15]+=x11.w;
      rs[16]+=x20.x; rs[17]+=x20.y; rs[18]+=x20.z; rs[19]+=x20.w;
      rs[20]+=x21.x; rs[21]+=x21.y; rs[22]+=x21.z; rs[23]+=x21.w;
    }
    bf16x8 a0 = pack8(x00,x01), a1 = pack8(x10,x11), a2 = pack8(x20,x21);
    #pragma unroll
    for (int ot=0; ot<6; ++ot){
      f32x4 acc = {0.f,0.f,0.f,0.f};
      acc = __builtin_amdgcn_mfma_f32_16x16x32_bf16(a0, wf[0][ot], acc, 0,0,0);
      acc = __builtin_amdgcn_mfma_f32_16x16x32_bf16(a1, wf[1][ot], acc, 0,0,0);
      acc = __builtin_amdgcn_mfma_f32_16x16x32_bf16(a2, wf[2][ot], acc, 0,0,0);
      sY[ot] += acc[0]+acc[1]+acc[2]+acc[3];
      sY2[ot] = fmaf(acc[0],acc[0], fmaf(acc[1],acc[1],
                fmaf(acc[2],acc[2], fmaf(acc[3],acc[3], sY2[ot]))));
    }
  }

  __shared__ float red[192];
  __shared__ float rsg[96];
  if (tid < 192) red[tid]=0.f;
  if (DO_SEG && tid < 96) rsg[tid]=0.f;
  __syncthreads();
  #pragma unroll
  for (int ot=0; ot<6; ++ot){
    float s = sY[ot], s2 = sY2[ot];
    s  += __shfl_xor(s,16);  s  += __shfl_xor(s,32);
    s2 += __shfl_xor(s2,16); s2 += __shfl_xor(s2,32);
    if (g==0){
      atomicAdd(&red[ot*16+lr], s);
      atomicAdd(&red[96+ot*16+lr], s2);
    }
  }
  if (DO_SEG){
    #pragma unroll
    for (int t=0; t<24; ++t){
      float s = rs[t];
      s += __shfl_xor(s,1); s += __shfl_xor(s,2);
      s += __shfl_xor(s,4); s += __shfl_xor(s,8);
      if (lr==0){
        int kt = t>>3, j = t&7;
        atomicAdd(&rsg[kt*32 + g*8 + j], s);
      }
    }
  }
  __syncthreads();
  if (tid<96){
    atomicAdd(gsum+tid,  red[tid]);
    atomicAdd(gsum2+tid, red[96+tid]);
    if (DO_SEG) atomicAdd(gseg + (blockIdx.x>>3)*96 + tid, rsg[tid]);
  }
}

// ---- MFMA head pass 2 (view2): relu(BN(y)) per-segment per-channel sums
__global__ __launch_bounds__(256) void head_apply_mfma(
    const float* __restrict__ X, const float* __restrict__ W,
    const float* __restrict__ scale, const float* __restrict__ shift,
    float* __restrict__ gseg)
{
  const int tid = threadIdx.x;
  const int l = tid & 63, w = tid >> 6;
  const int g = l >> 4, lr = l & 15;

  bf16x8 wf[3][6];
  #pragma unroll
  for (int ot=0; ot<6; ++ot){
    const float* wr = W + (ot*16+lr)*96 + g*8;
    #pragma unroll
    for (int kt=0; kt<3; ++kt){
      float4 w0 = *reinterpret_cast<const float4*>(wr + kt*32);
      float4 w1 = *reinterpret_cast<const float4*>(wr + kt*32 + 4);
      wf[kt][ot] = pack8(w0, w1);
    }
  }
  float sc[6], sh[6], zs[6];
  #pragma unroll
  for (int ot=0; ot<6; ++ot){
    sc[ot]=scale[ot*16+lr]; sh[ot]=shift[ot*16+lr]; zs[ot]=0.f;
  }

  const long base_row = (long)blockIdx.x*256 + w*16;
  #pragma unroll 1
  for (int it=0; it<4; ++it){
    const float* xr = X + (base_row + it*64 + lr)*96 + g*8;
    float4 x00 = *reinterpret_cast<const float4*>(xr);
    float4 x01 = *reinterpret_cast<const float4*>(xr+4);
    float4 x10 = *reinterpret_cast<const float4*>(xr+32);
    float4 x11 = *reinterpret_cast<const float4*>(xr+36);
    float4 x20 = *reinterpret_cast<const float4*>(xr+64);
    float4 x21 = *reinterpret_cast<const float4*>(xr+68);
    bf16x8 a0 = pack8(x00,x01), a1 = pack8(x10,x11), a2 = pack8(x20,x21);
    #pragma unroll
    for (int ot=0; ot<6; ++ot){
      f32x4 acc = {0.f,0.f,0.f,0.f};
      acc = __builtin_amdgcn_mfma_f32_16x16x32_bf16(a0, wf[0][ot], acc, 0,0,0);
      acc = __builtin_amdgcn_mfma_f32_16x16x32_bf16(a1, wf[1][ot], acc, 0,0,0);
      acc = __builtin_amdgcn_mfma_f32_16x16x32_bf16(a2, wf[2][ot], acc, 0,0,0);
      zs[ot] += fmaxf(fmaf(acc[0],sc[ot],sh[ot]),0.f)
              + fmaxf(fmaf(acc[1],sc[ot],sh[ot]),0.f)
              + fmaxf(fmaf(acc[2],sc[ot],sh[ot]),0.f)
              + fmaxf(fmaf(acc[3],sc[ot],sh[ot]),0.f);
    }
  }

  __shared__ float red[96];
  if (tid < 96) red[tid]=0.f;
  __syncthreads();
  #pragma unroll
  for (int ot=0; ot<6; ++ot){
    float s = zs[ot];
    s += __shfl_xor(s,16); s += __shfl_xor(s,32);
    if (g==0) atomicAdd(&red[ot*16+lr], s);
  }
  __syncthreads();
  if (tid<96) atomicAdd(gseg + (blockIdx.x>>3)*96 + tid, red[tid]);
}

// BN scale/shift from sums (training-mode batch stats, biased var)
__global__ void bn_params_kernel(const float* __restrict__ gq_gamma, const float* __restrict__ gq_beta,
                                 const float* __restrict__ gk_gamma, const float* __restrict__ gk_beta,
                                 float* __restrict__ ws)
{
  const int t = threadIdx.x;
  const float invN = 1.0f/(float)NPTS;
  if (t < 96){
    float mu  = ws[WS_GQ_SUM+t]*invN;
    float var = ws[WS_GQ_SUM2+t]*invN - mu*mu;
    float sc  = gq_gamma[t]*rsqrtf(var + 1e-5f);
    ws[WS_GQ_SCALE+t] = sc;
    ws[WS_GQ_SHIFT+t] = gq_beta[t] - mu*sc;
  } else if (t < 192){
    int c = t-96;
    float mu  = ws[WS_GK_SUM+c]*invN;
    float var = ws[WS_GK_SUM2+c]*invN - mu*mu;
    float sc  = gk_gamma[c]*rsqrtf(var + 1e-5f);
    ws[WS_GK_SCALE+c] = sc;
    ws[WS_GK_SHIFT+c] = gk_beta[c] - mu*sc;
  }
}

// anchor = l2norm(segsum/2048)
__global__ __launch_bounds__(128) void anchor_kernel(
    const float* __restrict__ segsum, float* __restrict__ dst)
{
  __shared__ float red[128];
  const int t = threadIdx.x, s = blockIdx.x;
  float m = 0.f;
  if (t<96) m = segsum[s*96+t] * (1.0f/2048.0f);
  red[t] = m*m;
  __syncthreads();
  for (int off=64; off>0; off>>=1){
    if (t<off) red[t]+=red[t+off];
    __syncthreads();
  }
  float inv = 1.0f/(sqrtf(red[0]) + 1e-7f);
  if (t<96) dst[s*96+t] = m*inv;
}

// ---- fp32 96x96 tile GEMM helpers (used only by samples_kernel) ----
__device__ __forceinline__ void fma_row(float4& acc, const float4 x,
    const float4 w0, const float4 w1, const float4 w2, const float4 w3){
  acc.x = fmaf(x.x,w0.x, fmaf(x.y,w1.x, fmaf(x.z,w2.x, fmaf(x.w,w3.x, acc.x))));
  acc.y = fmaf(x.x,w0.y, fmaf(x.y,w1.y, fmaf(x.z,w2.y, fmaf(x.w,w3.y, acc.y))));
  acc.z = fmaf(x.x,w0.z, fmaf(x.y,w1.z, fmaf(x.z,w2.z, fmaf(x.w,w3.z, acc.z))));
  acc.w = fmaf(x.x,w0.w, fmaf(x.y,w1.w, fmaf(x.z,w2.w, fmaf(x.w,w3.w, acc.w))));
}
__device__ __forceinline__ void load_W(const float* __restrict__ W, float* Ws, int tid){
  #pragma unroll
  for (int i=0;i<12;i++){
    int f = i*768 + tid*4;
    int oc = f/96, k = f%96;
    float4 w4 = *reinterpret_cast<const float4*>(W + f);
    Ws[(k+0)*100+oc]=w4.x; Ws[(k+1)*100+oc]=w4.y;
    Ws[(k+2)*100+oc]=w4.z; Ws[(k+3)*100+oc]=w4.w;
  }
}
__device__ __forceinline__ void gemm_tile(const float* Xs, const float* Ws,
    int ocg, int rowg, int r0, float4 acc[4]){
  const float4* Xs4 = reinterpret_cast<const float4*>(Xs);
  const float4* Ws4 = reinterpret_cast<const float4*>(Ws);
  acc[0]=acc[1]=acc[2]=acc[3]=make_float4(0.f,0.f,0.f,0.f);
  #pragma unroll 4
  for (int k4=0;k4<24;k4++){
    float4 w0 = Ws4[(k4*4+0)*25 + ocg];
    float4 w1 = Ws4[(k4*4+1)*25 + ocg];
    float4 w2 = Ws4[(k4*4+2)*25 + ocg];
    float4 w3 = Ws4[(k4*4+3)*25 + ocg];
    #pragma unroll
    for (int jj=0;jj<4;jj++){
      float4 xv = Xs4[(r0+jj)*25 + (k4 ^ rowg)];
      fma_row(acc[jj], xv, w0, w1, w2, w3);
    }
  }
}

// gather 32 sampled view1 rows -> raw l2norm + gk-head l2norm, stored ROW-MAJOR [7680][96]
__global__ __launch_bounds__(192) void samples_kernel(
    const float* __restrict__ V1, const float* __restrict__ W,
    const float* __restrict__ scale, const float* __restrict__ shift,
    const int* __restrict__ idxs,
    float* __restrict__ sampT, float* __restrict__ samp2T)
{
  __shared__ __align__(16) float Ws[9600];
  __shared__ __align__(16) float Xs[3200];
  __shared__ __align__(16) float Gs[3200];
  __shared__ float invr[32], invh[32];
  const int tid = threadIdx.x;
  const int ocg = tid % 24, rowg = tid / 24;
  const int oc0 = ocg*4,  r0  = rowg*4;
  load_W(W, Ws, tid);
  const int base = blockIdx.x * 32;
  #pragma unroll
  for (int i=0;i<4;i++){
    int f = i*768 + tid*4;
    int row = f/96, col = f%96;
    int g = idxs[base+row];
    float4 v = *reinterpret_cast<const float4*>(V1 + g*96 + col);
    *reinterpret_cast<float4*>(Xs + row*100 + (col ^ ((row>>2)<<2))) = v;
  }
  __syncthreads();
  if (tid<32){
    float s=0.f;
    #pragma unroll
    for (int k=0;k<96;k++){ float v=Xs[tid*100+(k^((tid>>2)<<2))]; s=fmaf(v,v,s); }
    invr[tid]=1.0f/(sqrtf(s)+1e-7f);
  }
  __syncthreads();
  {
    int rr=tid&31, kg=tid>>5;
    float inv=invr[rr];
    #pragma unroll
    for (int kk=0;kk<16;kk++){
      int k=kg*16+kk;
      sampT[(long)(base+rr)*96 + k] = Xs[rr*100 + (k ^ ((rr>>2)<<2))]*inv;
    }
  }
  float4 acc[4];
  gemm_tile(Xs, Ws, ocg, rowg, r0, acc);
  float4 sc = make_float4(scale[oc0],scale[oc0+1],scale[oc0+2],scale[oc0+3]);
  float4 sh = make_float4(shift[oc0],shift[oc0+1],shift[oc0+2],shift[oc0+3]);
  #pragma unroll
  for (int jj=0;jj<4;jj++){
    int rr=r0+jj;
    float4 g;
    g.x=fmaxf(fmaf(acc[jj].x,sc.x,sh.x),0.f);
    g.y=fmaxf(fmaf(acc[jj].y,sc.y,sh.y),0.f);
    g.z=fmaxf(fmaf(acc[jj].z,sc.z,sh.z),0.f);
    g.w=fmaxf(fmaf(acc[jj].w,sc.w,sh.w),0.f);
    *reinterpret_cast<float4*>(Gs + rr*100 + (oc0 ^ ((rr>>2)<<2))) = g;
  }
  __syncthreads();
  if (tid<32){
    float s=0.f;
    #pragma unroll
    for (int k=0;k<96;k++){ float v=Gs[tid*100+(k^((tid>>2)<<2))]; s=fmaf(v,v,s); }
    invh[tid]=1.0f/(sqrtf(s)+1e-7f);
  }
  __syncthreads();
  {
    int rr=tid&31, kg=tid>>5;
    float inv=invh[rr];
    #pragma unroll
    for (int kk=0;kk<16;kk++){
      int k=kg*16+kk;
      samp2T[(long)(base+rr)*96 + k] = Gs[rr*100 + (k ^ ((rr>>2)<<2))]*inv;
    }
  }
}

// ---- sim2 = anchor2 @ samples2^T via MFMA: grid (30 col-tiles, 16 row-tiles) ----
__global__ __launch_bounds__(256) void sim2_mfma(
    const float* __restrict__ anchor2, const float* __restrict__ samp2,  // samp2 [7680][96]
    float* __restrict__ srowG)
{
  const int tid = threadIdx.x;
  const int l = tid & 63, w = tid >> 6;
  const int g = l >> 4, lr = l & 15;
  const int rowbase = blockIdx.y * 16;
  const int colbase = blockIdx.x * 256 + w * 64;

  // A frags: lane row = lr, k = kt*32 + g*8 + j
  bf16x8 af[3];
  const float* ar = anchor2 + (rowbase + lr)*96 + g*8;
  #pragma unroll
  for (int kt=0; kt<3; ++kt){
    float4 a0 = *reinterpret_cast<const float4*>(ar + kt*32);
    float4 a1 = *reinterpret_cast<const float4*>(ar + kt*32 + 4);
    af[kt] = pack8(a0,a1);
  }
  #pragma unroll
  for (int sub=0; sub<4; ++sub){
    const float* br = samp2 + (long)(colbase + sub*16 + lr)*96 + g*8;
    float4 b00 = *reinterpret_cast<const float4*>(br);
    float4 b01 = *reinterpret_cast<const float4*>(br+4);
    float4 b10 = *reinterpret_cast<const float4*>(br+32);
    float4 b11 = *reinterpret_cast<const float4*>(br+36);
    float4 b20 = *reinterpret_cast<const float4*>(br+64);
    float4 b21 = *reinterpret_cast<const float4*>(br+68);
    f32x4 acc = {0.f,0.f,0.f,0.f};
    acc = __builtin_amdgcn_mfma_f32_16x16x32_bf16(af[0], pack8(b00,b01), acc, 0,0,0);
    acc = __builtin_amdgcn_mfma_f32_16x16x32_bf16(af[1], pack8(b10,b11), acc, 0,0,0);
    acc = __builtin_amdgcn_mfma_f32_16x16x32_bf16(af[2], pack8(b20,b21), acc, 0,0,0);
    const int col  = colbase + sub*16 + lr;
    const int row0 = rowbase + g*4;
    #pragma unroll
    for (int i=0;i<4;i++)
      srowG[(long)(row0+i)*SK + col] = acc[i];
  }
}

// Lcon: 60 relevant columns per row (30 diag positives + 30 linspace negatives)
__global__ __launch_bounds__(64) void lcon1_kernel(
    const float* __restrict__ anchor, const float* __restrict__ sampT, float* __restrict__ out)
{
  __shared__ float a[96];
  const int tid = threadIdx.x, r = blockIdx.x;
  for (int i=tid;i<96;i+=64) a[i]=anchor[r*96+i];
  __syncthreads();
  int c = 0;
  if (tid<30) c = r*30+tid;
  else if (tid<60){
    int j = tid-30;
    int p = (int)((double)j * 7649.0 / 29.0);   // linspace(0, M-1, 30).astype(int32)
    c = (p < r*30) ? p : p+30;                  // skip own block
  }
  float s=0.f;
  if (tid<60){
    const float* sr = sampT + (long)c*96;
    #pragma unroll
    for (int k4=0;k4<24;k4++){
      float4 v = *reinterpret_cast<const float4*>(sr + k4*4);
      s = fmaf(a[k4*4+0],v.x, fmaf(a[k4*4+1],v.y,
          fmaf(a[k4*4+2],v.z, fmaf(a[k4*4+3],v.w, s))));
    }
  }
  float logit = 2.0f*s;                          // /T, T=0.5
  float se = (tid<60) ? expf(logit) : 0.f;
  float sp = (tid<30) ? logit : 0.f;
  #pragma unroll
  for (int off=32; off; off>>=1){ se += __shfl_xor(se,off); sp += __shfl_xor(sp,off); }
  if (tid==0){
    float row = sp*(1.0f/30.0f) - logf(se);
    atomicAdd(out, -row*(1.0f/256.0f));
  }
}

// Lcon2 selection/softmax over precomputed sim2 row
__global__ __launch_bounds__(256) void lcon2_kernel(
    const float* __restrict__ srowG, const int* __restrict__ bg, float* __restrict__ out)
{
  __shared__ float wvv[4];
  __shared__ int   wcc[4];
  __shared__ int   winc_s;
  __shared__ int   sel[30];
  const int tid = threadIdx.x, r = blockIdx.x;
  const int lane = tid & 63, wid = tid >> 6;
  const float* __restrict__ rowp = srowG + (long)r*SK;
  float val[30];
  #pragma unroll
  for (int j=0;j<30;j++) val[j] = rowp[(j<<8) + tid];
  unsigned mask=0; float possum=0.f;
  for (int it=0; it<30; ++it){
    float bv = -3.0e38f; int bc = 1<<30;
    #pragma unroll
    for (int j=0;j<30;j++){
      if (!((mask>>j)&1u)){
        float v = val[j]; int c = tid + (j<<8);
        if (v > bv || (v == bv && c < bc)){ bv=v; bc=c; }
      }
    }
    #pragma unroll
    for (int off=32; off; off>>=1){
      float ov = __shfl_xor(bv, off); int ocx = __shfl_xor(bc, off);
      if (ov > bv || (ov == bv && ocx < bc)){ bv=ov; bc=ocx; }
    }
    if (lane==0){ wvv[wid]=bv; wcc[wid]=bc; }
    __syncthreads();
    if (tid==0){
      float v=wvv[0]; int c=wcc[0];
      #pragma unroll
      for (int w=1;w<4;w++){
        if (wvv[w]>v || (wvv[w]==v && wcc[w]<c)){ v=wvv[w]; c=wcc[w]; }
      }
      winc_s=c; sel[it]=c; possum += v;
    }
    __syncthreads();
    int c = winc_s;
    if ((c & 255) == tid) mask |= 1u << (c >> 8);
  }
  const int bgr = bg[r];
  float se=0.f;
  #pragma unroll
  for (int j=0;j<30;j++){
    int c = tid + (j<<8);
    int seg = c/30;
    int bgc = bg[seg];
    bool nf = ((bgr!=0) ? (bgc==0) : (bgc!=0)) && (seg != r);
    if (nf) se += expf(2.0f*val[j]);
  }
  #pragma unroll
  for (int off=32; off; off>>=1) se += __shfl_xor(se, off);
  if (lane==0) wvv[wid]=se;
  __syncthreads();
  float ex=0.f;
  if (tid<30){
    int c = sel[tid]; int seg=c/30; int bgc=bg[seg];
    bool nf = ((bgr!=0) ? (bgc==0) : (bgc!=0)) && (seg != r);
    if (!nf) ex = expf(2.0f*rowp[c]);        // positive not already in denom via neg
  }
  if (wid==0){
    #pragma unroll
    for (int off=32; off; off>>=1) ex += __shfl_xor(ex, off);
  }
  if (tid==0){
    float lse = logf(wvv[0]+wvv[1]+wvv[2]+wvv[3] + ex);
    float row = possum*(2.0f/30.0f) - lse;
    atomicAdd(out, -row*(1.0f/256.0f));
  }
}

extern "C" void kernel_launch(void* const* d_in, const int* in_sizes, int n_in,
                              void* d_out, int out_size, void* d_ws, size_t ws_size,
                              hipStream_t stream) {
  (void)in_sizes; (void)n_in; (void)out_size; (void)ws_size;
  const float* v1       = (const float*)d_in[0];
  const float* v2       = (const float*)d_in[1];
  const float* gq_w     = (const float*)d_in[2];
  const float* gq_gamma = (const float*)d_in[4];
  const float* gq_beta  = (const float*)d_in[5];
  const float* gk_w     = (const float*)d_in[6];
  const float* gk_gamma = (const float*)d_in[8];
  const float* gk_beta  = (const float*)d_in[9];
  const int*   idxs     = (const int*)d_in[12];
  const int*   bg       = (const int*)d_in[13];
  float* ws  = (float*)d_ws;
  float* out = (float*)d_out;

  hipMemsetAsync(ws, 0, (size_t)WS_ANCHOR1*sizeof(float), stream);  // sums + segsums
  hipMemsetAsync(out, 0, sizeof(float), stream);

  head_stats_mfma<true ><<<2048,256,0,stream>>>(v2, gq_w, ws+WS_GQ_SUM, ws+WS_GQ_SUM2, ws+WS_SEGX2);
  head_stats_mfma<false><<<2048,256,0,stream>>>(v1, gk_w, ws+WS_GK_SUM, ws+WS_GK_SUM2, nullptr);
  bn_params_kernel<<<1,192,0,stream>>>(gq_gamma, gq_beta, gk_gamma, gk_beta, ws);
  anchor_kernel<<<256,128,0,stream>>>(ws+WS_SEGX2, ws+WS_ANCHOR1);
  head_apply_mfma<<<2048,256,0,stream>>>(v2, gq_w, ws+WS_GQ_SCALE, ws+WS_GQ_SHIFT, ws+WS_SEGG2);
  anchor_kernel<<<256,128,0,stream>>>(ws+WS_SEGG2, ws+WS_ANCHOR2);
  samples_kernel<<<240,192,0,stream>>>(v1, gk_w, ws+WS_GK_SCALE, ws+WS_GK_SHIFT, idxs,
                                       ws+WS_SAMPT, ws+WS_SAMP2T);
  sim2_mfma<<<dim3(30,16),256,0,stream>>>(ws+WS_ANCHOR2, ws+WS_SAMP2T, ws+WS_SROW);
  lcon1_kernel<<<256,64,0,stream>>>(ws+WS_ANCHOR1, ws+WS_SAMPT, out);
  lcon2_kernel<<<256,256,0,stream>>>(ws+WS_SROW, bg, out);
}

// Round 5
// 351.881 us; speedup vs baseline: 4.8867x; 1.0687x over previous
//
#include <hip/hip_runtime.h>
#include <math.h>

#define SK 7680          // 256 segments * 30 samples
#define NPTS 524288

// ---- workspace float offsets ----
#define WS_GQ_PART  0         // 32 partials x (96 sum + 96 sumsq)
#define WS_GK_PART  6144
#define WS_GQ_SCALE 12288
#define WS_GQ_SHIFT 12384
#define WS_GK_SCALE 12480
#define WS_GK_SHIFT 12576
#define WS_WQF      12672     // 18 frags x 64 lanes x 16B (bf16x8)
#define WS_WKF      17280
#define WS_SEGX2    21888     // 256*96 raw view2 segment sums
#define WS_SEGG2    46464     // 256*96 head(view2) segment sums
#define WS_ANCHOR1  71040
#define WS_ANCHOR2  95616
#define WS_SAMPT    120192    // [7680][96] raw l2normed samples (row-major)
#define WS_SAMP2T   857472    // [7680][96] head l2normed samples (row-major)
#define WS_SROW     1594752   // [256][7680] sim2 matrix
#define WS_ZERO_CNT 71040     // zero partials + seg sums (covers W frag bufs harmlessly)

typedef __attribute__((ext_vector_type(8))) short bf16x8;
typedef __attribute__((ext_vector_type(4))) float f32x4;

__device__ __forceinline__ ushort f2bf(float f){
  union { float f; unsigned u; } v; v.f = f;
  unsigned r = (v.u + 0x7fffu + ((v.u >> 16) & 1u)) >> 16;   // RNE
  return (ushort)r;
}
__device__ __forceinline__ bf16x8 pack8(float4 a, float4 b){
  bf16x8 r;
  r[0]=(short)f2bf(a.x); r[1]=(short)f2bf(a.y); r[2]=(short)f2bf(a.z); r[3]=(short)f2bf(a.w);
  r[4]=(short)f2bf(b.x); r[5]=(short)f2bf(b.y); r[6]=(short)f2bf(b.z); r[7]=(short)f2bf(b.w);
  return r;
}
__device__ __forceinline__ float4 ld4(const float* p){
  return *reinterpret_cast<const float4*>(p);
}

// ---- precompute bf16 W fragments: frag (kt,ot), lane l holds W[ot*16+(l&15)][kt*32+(l>>4)*8 + j]
__global__ __launch_bounds__(64) void wfrag_prep(
    const float* __restrict__ Wq, const float* __restrict__ Wk,
    float* __restrict__ outq, float* __restrict__ outk)
{
  const int l = threadIdx.x;
  const float* W  = blockIdx.x ? Wk : Wq;
  float* out      = blockIdx.x ? outk : outq;
  const int g = l >> 4, lr = l & 15;
  #pragma unroll
  for (int ot=0; ot<6; ++ot){
    const float* wr = W + (ot*16+lr)*96 + g*8;
    #pragma unroll
    for (int kt=0; kt<3; ++kt){
      bf16x8 f = pack8(ld4(wr + kt*32), ld4(wr + kt*32 + 4));
      *reinterpret_cast<bf16x8*>(out + ((kt*6+ot)*64 + l)*4) = f;
    }
  }
}

// ---- MFMA head pass 1: per-channel sum/sumsq of y = x @ W^T (bias cancels in BN),
// optionally fused raw-x per-segment sums. Register double-buffered X prefetch.
template<bool DO_SEG>
__global__ __launch_bounds__(256, 3) void head_stats_mfma(
    const float* __restrict__ X, const float* __restrict__ wfrag,
    float* __restrict__ gpart, float* __restrict__ gseg)
{
  const int tid = threadIdx.x;
  const int l = tid & 63, w = tid >> 6;
  const int g = l >> 4, lr = l & 15;

  bf16x8 wf[3][6];
  #pragma unroll
  for (int kt=0; kt<3; ++kt)
    #pragma unroll
    for (int ot=0; ot<6; ++ot)
      wf[kt][ot] = *reinterpret_cast<const bf16x8*>(wfrag + ((kt*6+ot)*64 + l)*4);

  float sY[6], sY2[6];
  #pragma unroll
  for (int ot=0; ot<6; ++ot){ sY[ot]=0.f; sY2[ot]=0.f; }
  float rs[24];
  if (DO_SEG){
    #pragma unroll
    for (int t=0; t<24; ++t) rs[t]=0.f;
  }

  const long base_row = (long)blockIdx.x*256 + w*16 + lr;
  const float* xr = X + base_row*96 + g*8;

  float4 c0=ld4(xr), c1=ld4(xr+4), c2=ld4(xr+32), c3=ld4(xr+36), c4=ld4(xr+64), c5=ld4(xr+68);

  #pragma unroll 1
  for (int it=0; it<4; ++it){
    float4 n0,n1,n2,n3,n4,n5;
    if (it<3){
      const float* xn = xr + (it+1)*6144;      // +64 rows
      n0=ld4(xn); n1=ld4(xn+4); n2=ld4(xn+32); n3=ld4(xn+36); n4=ld4(xn+64); n5=ld4(xn+68);
    }
    if (DO_SEG){
      rs[0]+=c0.x; rs[1]+=c0.y; rs[2]+=c0.z; rs[3]+=c0.w;
      rs[4]+=c1.x; rs[5]+=c1.y; rs[6]+=c1.z; rs[7]+=c1.w;
      rs[8]+=c2.x; rs[9]+=c2.y; rs[10]+=c2.z; rs[11]+=c2.w;
      rs[12]+=c3.x; rs[13]+=c3.y; rs[14]+=c3.z; rs[15]+=c3.w;
      rs[16]+=c4.x; rs[17]+=c4.y; rs[18]+=c4.z; rs[19]+=c4.w;
      rs[20]+=c5.x; rs[21]+=c5.y; rs[22]+=c5.z; rs[23]+=c5.w;
    }
    bf16x8 a0 = pack8(c0,c1), a1 = pack8(c2,c3), a2 = pack8(c4,c5);
    #pragma unroll
    for (int ot=0; ot<6; ++ot){
      f32x4 acc = {0.f,0.f,0.f,0.f};
      acc = __builtin_amdgcn_mfma_f32_16x16x32_bf16(a0, wf[0][ot], acc, 0,0,0);
      acc = __builtin_amdgcn_mfma_f32_16x16x32_bf16(a1, wf[1][ot], acc, 0,0,0);
      acc = __builtin_amdgcn_mfma_f32_16x16x32_bf16(a2, wf[2][ot], acc, 0,0,0);
      sY[ot] += acc[0]+acc[1]+acc[2]+acc[3];
      sY2[ot] = fmaf(acc[0],acc[0], fmaf(acc[1],acc[1],
                fmaf(acc[2],acc[2], fmaf(acc[3],acc[3], sY2[ot]))));
    }
    if (it<3){ c0=n0; c1=n1; c2=n2; c3=n3; c4=n4; c5=n5; }
  }

  __shared__ float red[192];
  __shared__ float rsg[96];
  if (tid < 192) red[tid]=0.f;
  if (DO_SEG && tid < 96) rsg[tid]=0.f;
  __syncthreads();
  #pragma unroll
  for (int ot=0; ot<6; ++ot){
    float s = sY[ot], s2 = sY2[ot];
    s  += __shfl_xor(s,16);  s  += __shfl_xor(s,32);
    s2 += __shfl_xor(s2,16); s2 += __shfl_xor(s2,32);
    if (g==0){
      atomicAdd(&red[ot*16+lr], s);
      atomicAdd(&red[96+ot*16+lr], s2);
    }
  }
  if (DO_SEG){
    #pragma unroll
    for (int t=0; t<24; ++t){
      float s = rs[t];
      s += __shfl_xor(s,1); s += __shfl_xor(s,2);
      s += __shfl_xor(s,4); s += __shfl_xor(s,8);
      if (lr==0){
        int kt = t>>3, j = t&7;
        atomicAdd(&rsg[kt*32 + g*8 + j], s);
      }
    }
  }
  __syncthreads();
  if (tid<96){
    float* dst = gpart + (blockIdx.x & 31)*192;   // 32-way de-contended partials
    atomicAdd(dst+tid,    red[tid]);
    atomicAdd(dst+96+tid, red[96+tid]);
    if (DO_SEG) atomicAdd(gseg + (blockIdx.x>>3)*96 + tid, rsg[tid]);
  }
}

// ---- MFMA head pass 2 (view2): relu(BN(y)) per-segment per-channel sums
__global__ __launch_bounds__(256, 3) void head_apply_mfma(
    const float* __restrict__ X, const float* __restrict__ wfrag,
    const float* __restrict__ scale, const float* __restrict__ shift,
    float* __restrict__ gseg)
{
  const int tid = threadIdx.x;
  const int l = tid & 63, w = tid >> 6;
  const int g = l >> 4, lr = l & 15;

  bf16x8 wf[3][6];
  #pragma unroll
  for (int kt=0; kt<3; ++kt)
    #pragma unroll
    for (int ot=0; ot<6; ++ot)
      wf[kt][ot] = *reinterpret_cast<const bf16x8*>(wfrag + ((kt*6+ot)*64 + l)*4);

  float sc[6], sh[6], zs[6];
  #pragma unroll
  for (int ot=0; ot<6; ++ot){
    sc[ot]=scale[ot*16+lr]; sh[ot]=shift[ot*16+lr]; zs[ot]=0.f;
  }

  const long base_row = (long)blockIdx.x*256 + w*16 + lr;
  const float* xr = X + base_row*96 + g*8;

  float4 c0=ld4(xr), c1=ld4(xr+4), c2=ld4(xr+32), c3=ld4(xr+36), c4=ld4(xr+64), c5=ld4(xr+68);

  #pragma unroll 1
  for (int it=0; it<4; ++it){
    float4 n0,n1,n2,n3,n4,n5;
    if (it<3){
      const float* xn = xr + (it+1)*6144;
      n0=ld4(xn); n1=ld4(xn+4); n2=ld4(xn+32); n3=ld4(xn+36); n4=ld4(xn+64); n5=ld4(xn+68);
    }
    bf16x8 a0 = pack8(c0,c1), a1 = pack8(c2,c3), a2 = pack8(c4,c5);
    #pragma unroll
    for (int ot=0; ot<6; ++ot){
      f32x4 acc = {0.f,0.f,0.f,0.f};
      acc = __builtin_amdgcn_mfma_f32_16x16x32_bf16(a0, wf[0][ot], acc, 0,0,0);
      acc = __builtin_amdgcn_mfma_f32_16x16x32_bf16(a1, wf[1][ot], acc, 0,0,0);
      acc = __builtin_amdgcn_mfma_f32_16x16x32_bf16(a2, wf[2][ot], acc, 0,0,0);
      zs[ot] += fmaxf(fmaf(acc[0],sc[ot],sh[ot]),0.f)
              + fmaxf(fmaf(acc[1],sc[ot],sh[ot]),0.f)
              + fmaxf(fmaf(acc[2],sc[ot],sh[ot]),0.f)
              + fmaxf(fmaf(acc[3],sc[ot],sh[ot]),0.f);
    }
    if (it<3){ c0=n0; c1=n1; c2=n2; c3=n3; c4=n4; c5=n5; }
  }

  __shared__ float red[96];
  if (tid < 96) red[tid]=0.f;
  __syncthreads();
  #pragma unroll
  for (int ot=0; ot<6; ++ot){
    float s = zs[ot];
    s += __shfl_xor(s,16); s += __shfl_xor(s,32);
    if (g==0) atomicAdd(&red[ot*16+lr], s);
  }
  __syncthreads();
  if (tid<96) atomicAdd(gseg + (blockIdx.x>>3)*96 + tid, red[tid]);
}

// BN scale/shift from 32 partial sums (training-mode batch stats, biased var)
__global__ void bn_params_kernel(const float* __restrict__ gq_gamma, const float* __restrict__ gq_beta,
                                 const float* __restrict__ gk_gamma, const float* __restrict__ gk_beta,
                                 float* __restrict__ ws)
{
  const int t = threadIdx.x;
  const float invN = 1.0f/(float)NPTS;
  if (t < 96){
    float s=0.f, s2=0.f;
    #pragma unroll 4
    for (int p=0;p<32;p++){
      s  += ws[WS_GQ_PART + p*192 + t];
      s2 += ws[WS_GQ_PART + p*192 + 96 + t];
    }
    float mu  = s*invN;
    float var = s2*invN - mu*mu;
    float sc  = gq_gamma[t]*rsqrtf(var + 1e-5f);
    ws[WS_GQ_SCALE+t] = sc;
    ws[WS_GQ_SHIFT+t] = gq_beta[t] - mu*sc;
  } else if (t < 192){
    int c = t-96;
    float s=0.f, s2=0.f;
    #pragma unroll 4
    for (int p=0;p<32;p++){
      s  += ws[WS_GK_PART + p*192 + c];
      s2 += ws[WS_GK_PART + p*192 + 96 + c];
    }
    float mu  = s*invN;
    float var = s2*invN - mu*mu;
    float sc  = gk_gamma[c]*rsqrtf(var + 1e-5f);
    ws[WS_GK_SCALE+c] = sc;
    ws[WS_GK_SHIFT+c] = gk_beta[c] - mu*sc;
  }
}

// anchor = l2norm(segsum/2048)
__global__ __launch_bounds__(128) void anchor_kernel(
    const float* __restrict__ segsum, float* __restrict__ dst)
{
  __shared__ float red[128];
  const int t = threadIdx.x, s = blockIdx.x;
  float m = 0.f;
  if (t<96) m = segsum[s*96+t] * (1.0f/2048.0f);
  red[t] = m*m;
  __syncthreads();
  for (int off=64; off>0; off>>=1){
    if (t<off) red[t]+=red[t+off];
    __syncthreads();
  }
  float inv = 1.0f/(sqrtf(red[0]) + 1e-7f);
  if (t<96) dst[s*96+t] = m*inv;
}

// ---- fp32 96x96 tile GEMM helpers (used only by samples_kernel) ----
__device__ __forceinline__ void fma_row(float4& acc, const float4 x,
    const float4 w0, const float4 w1, const float4 w2, const float4 w3){
  acc.x = fmaf(x.x,w0.x, fmaf(x.y,w1.x, fmaf(x.z,w2.x, fmaf(x.w,w3.x, acc.x))));
  acc.y = fmaf(x.x,w0.y, fmaf(x.y,w1.y, fmaf(x.z,w2.y, fmaf(x.w,w3.y, acc.y))));
  acc.z = fmaf(x.x,w0.z, fmaf(x.y,w1.z, fmaf(x.z,w2.z, fmaf(x.w,w3.z, acc.z))));
  acc.w = fmaf(x.x,w0.w, fmaf(x.y,w1.w, fmaf(x.z,w2.w, fmaf(x.w,w3.w, acc.w))));
}
__device__ __forceinline__ void load_W(const float* __restrict__ W, float* Ws, int tid){
  #pragma unroll
  for (int i=0;i<12;i++){
    int f = i*768 + tid*4;
    int oc = f/96, k = f%96;
    float4 w4 = *reinterpret_cast<const float4*>(W + f);
    Ws[(k+0)*100+oc]=w4.x; Ws[(k+1)*100+oc]=w4.y;
    Ws[(k+2)*100+oc]=w4.z; Ws[(k+3)*100+oc]=w4.w;
  }
}
__device__ __forceinline__ void gemm_tile(const float* Xs, const float* Ws,
    int ocg, int rowg, int r0, float4 acc[4]){
  const float4* Xs4 = reinterpret_cast<const float4*>(Xs);
  const float4* Ws4 = reinterpret_cast<const float4*>(Ws);
  acc[0]=acc[1]=acc[2]=acc[3]=make_float4(0.f,0.f,0.f,0.f);
  #pragma unroll 4
  for (int k4=0;k4<24;k4++){
    float4 w0 = Ws4[(k4*4+0)*25 + ocg];
    float4 w1 = Ws4[(k4*4+1)*25 + ocg];
    float4 w2 = Ws4[(k4*4+2)*25 + ocg];
    float4 w3 = Ws4[(k4*4+3)*25 + ocg];
    #pragma unroll
    for (int jj=0;jj<4;jj++){
      float4 xv = Xs4[(r0+jj)*25 + (k4 ^ rowg)];
      fma_row(acc[jj], xv, w0, w1, w2, w3);
    }
  }
}

// gather 32 sampled view1 rows -> raw l2norm + gk-head l2norm, stored ROW-MAJOR [7680][96]
__global__ __launch_bounds__(192) void samples_kernel(
    const float* __restrict__ V1, const float* __restrict__ W,
    const float* __restrict__ scale, const float* __restrict__ shift,
    const int* __restrict__ idxs,
    float* __restrict__ sampT, float* __restrict__ samp2T)
{
  __shared__ __align__(16) float Ws[9600];
  __shared__ __align__(16) float Xs[3200];
  __shared__ __align__(16) float Gs[3200];
  __shared__ float invr[32], invh[32];
  const int tid = threadIdx.x;
  const int ocg = tid % 24, rowg = tid / 24;
  const int oc0 = ocg*4,  r0  = rowg*4;
  load_W(W, Ws, tid);
  const int base = blockIdx.x * 32;
  #pragma unroll
  for (int i=0;i<4;i++){
    int f = i*768 + tid*4;
    int row = f/96, col = f%96;
    int g = idxs[base+row];
    float4 v = *reinterpret_cast<const float4*>(V1 + g*96 + col);
    *reinterpret_cast<float4*>(Xs + row*100 + (col ^ ((row>>2)<<2))) = v;
  }
  __syncthreads();
  if (tid<32){
    float s=0.f;
    #pragma unroll
    for (int k=0;k<96;k++){ float v=Xs[tid*100+(k^((tid>>2)<<2))]; s=fmaf(v,v,s); }
    invr[tid]=1.0f/(sqrtf(s)+1e-7f);
  }
  __syncthreads();
  {
    int rr=tid&31, kg=tid>>5;
    float inv=invr[rr];
    #pragma unroll
    for (int kk=0;kk<16;kk++){
      int k=kg*16+kk;
      sampT[(long)(base+rr)*96 + k] = Xs[rr*100 + (k ^ ((rr>>2)<<2))]*inv;
    }
  }
  float4 acc[4];
  gemm_tile(Xs, Ws, ocg, rowg, r0, acc);
  float4 sc = make_float4(scale[oc0],scale[oc0+1],scale[oc0+2],scale[oc0+3]);
  float4 sh = make_float4(shift[oc0],shift[oc0+1],shift[oc0+2],shift[oc0+3]);
  #pragma unroll
  for (int jj=0;jj<4;jj++){
    int rr=r0+jj;
    float4 g;
    g.x=fmaxf(fmaf(acc[jj].x,sc.x,sh.x),0.f);
    g.y=fmaxf(fmaf(acc[jj].y,sc.y,sh.y),0.f);
    g.z=fmaxf(fmaf(acc[jj].z,sc.z,sh.z),0.f);
    g.w=fmaxf(fmaf(acc[jj].w,sc.w,sh.w),0.f);
    *reinterpret_cast<float4*>(Gs + rr*100 + (oc0 ^ ((rr>>2)<<2))) = g;
  }
  __syncthreads();
  if (tid<32){
    float s=0.f;
    #pragma unroll
    for (int k=0;k<96;k++){ float v=Gs[tid*100+(k^((tid>>2)<<2))]; s=fmaf(v,v,s); }
    invh[tid]=1.0f/(sqrtf(s)+1e-7f);
  }
  __syncthreads();
  {
    int rr=tid&31, kg=tid>>5;
    float inv=invh[rr];
    #pragma unroll
    for (int kk=0;kk<16;kk++){
      int k=kg*16+kk;
      samp2T[(long)(base+rr)*96 + k] = Gs[rr*100 + (k ^ ((rr>>2)<<2))]*inv;
    }
  }
}

// ---- sim2 = anchor2 @ samples2^T via MFMA: grid (30 col-tiles, 16 row-tiles) ----
__global__ __launch_bounds__(256) void sim2_mfma(
    const float* __restrict__ anchor2, const float* __restrict__ samp2,  // samp2 [7680][96]
    float* __restrict__ srowG)
{
  const int tid = threadIdx.x;
  const int l = tid & 63, w = tid >> 6;
  const int g = l >> 4, lr = l & 15;
  const int rowbase = blockIdx.y * 16;
  const int colbase = blockIdx.x * 256 + w * 64;

  bf16x8 af[3];
  const float* ar = anchor2 + (rowbase + lr)*96 + g*8;
  #pragma unroll
  for (int kt=0; kt<3; ++kt)
    af[kt] = pack8(ld4(ar + kt*32), ld4(ar + kt*32 + 4));

  #pragma unroll
  for (int sub=0; sub<4; ++sub){
    const float* br = samp2 + (long)(colbase + sub*16 + lr)*96 + g*8;
    float4 b00 = ld4(br);    float4 b01 = ld4(br+4);
    float4 b10 = ld4(br+32); float4 b11 = ld4(br+36);
    float4 b20 = ld4(br+64); float4 b21 = ld4(br+68);
    f32x4 acc = {0.f,0.f,0.f,0.f};
    acc = __builtin_amdgcn_mfma_f32_16x16x32_bf16(af[0], pack8(b00,b01), acc, 0,0,0);
    acc = __builtin_amdgcn_mfma_f32_16x16x32_bf16(af[1], pack8(b10,b11), acc, 0,0,0);
    acc = __builtin_amdgcn_mfma_f32_16x16x32_bf16(af[2], pack8(b20,b21), acc, 0,0,0);
    const int col  = colbase + sub*16 + lr;
    const int row0 = rowbase + g*4;
    #pragma unroll
    for (int i=0;i<4;i++)
      srowG[(long)(row0+i)*SK + col] = acc[i];
  }
}

// Lcon: 60 relevant columns per row (30 diag positives + 30 linspace negatives)
__global__ __launch_bounds__(64) void lcon1_kernel(
    const float* __restrict__ anchor, const float* __restrict__ sampT, float* __restrict__ out)
{
  __shared__ float a[96];
  const int tid = threadIdx.x, r = blockIdx.x;
  for (int i=tid;i<96;i+=64) a[i]=anchor[r*96+i];
  __syncthreads();
  int c = 0;
  if (tid<30) c = r*30+tid;
  else if (tid<60){
    int j = tid-30;
    int p = (int)((double)j * 7649.0 / 29.0);   // linspace(0, M-1, 30).astype(int32)
    c = (p < r*30) ? p : p+30;                  // skip own block
  }
  float s=0.f;
  if (tid<60){
    const float* sr = sampT + (long)c*96;
    #pragma unroll
    for (int k4=0;k4<24;k4++){
      float4 v = *reinterpret_cast<const float4*>(sr + k4*4);
      s = fmaf(a[k4*4+0],v.x, fmaf(a[k4*4+1],v.y,
          fmaf(a[k4*4+2],v.z, fmaf(a[k4*4+3],v.w, s))));
    }
  }
  float logit = 2.0f*s;                          // /T, T=0.5
  float se = (tid<60) ? expf(logit) : 0.f;
  float sp = (tid<30) ? logit : 0.f;
  #pragma unroll
  for (int off=32; off; off>>=1){ se += __shfl_xor(se,off); sp += __shfl_xor(sp,off); }
  if (tid==0){
    float row = sp*(1.0f/30.0f) - logf(se);
    atomicAdd(out, -row*(1.0f/256.0f));
  }
}

// Lcon2 selection/softmax over precomputed sim2 row
__global__ __launch_bounds__(256) void lcon2_kernel(
    const float* __restrict__ srowG, const int* __restrict__ bg, float* __restrict__ out)
{
  __shared__ float wvv[4];
  __shared__ int   wcc[4];
  __shared__ int   winc_s;
  __shared__ int   sel[30];
  const int tid = threadIdx.x, r = blockIdx.x;
  const int lane = tid & 63, wid = tid >> 6;
  const float* __restrict__ rowp = srowG + (long)r*SK;
  float val[30];
  #pragma unroll
  for (int j=0;j<30;j++) val[j] = rowp[(j<<8) + tid];
  unsigned mask=0; float possum=0.f;
  for (int it=0; it<30; ++it){
    float bv = -3.0e38f; int bc = 1<<30;
    #pragma unroll
    for (int j=0;j<30;j++){
      if (!((mask>>j)&1u)){
        float v = val[j]; int c = tid + (j<<8);
        if (v > bv || (v == bv && c < bc)){ bv=v; bc=c; }
      }
    }
    #pragma unroll
    for (int off=32; off; off>>=1){
      float ov = __shfl_xor(bv, off); int ocx = __shfl_xor(bc, off);
      if (ov > bv || (ov == bv && ocx < bc)){ bv=ov; bc=ocx; }
    }
    if (lane==0){ wvv[wid]=bv; wcc[wid]=bc; }
    __syncthreads();
    if (tid==0){
      float v=wvv[0]; int c=wcc[0];
      #pragma unroll
      for (int w=1;w<4;w++){
        if (wvv[w]>v || (wvv[w]==v && wcc[w]<c)){ v=wvv[w]; c=wcc[w]; }
      }
      winc_s=c; sel[it]=c; possum += v;
    }
    __syncthreads();
    int c = winc_s;
    if ((c & 255) == tid) mask |= 1u << (c >> 8);
  }
  const int bgr = bg[r];
  float se=0.f;
  #pragma unroll
  for (int j=0;j<30;j++){
    int c = tid + (j<<8);
    int seg = c/30;
    int bgc = bg[seg];
    bool nf = ((bgr!=0) ? (bgc==0) : (bgc!=0)) && (seg != r);
    if (nf) se += expf(2.0f*val[j]);
  }
  #pragma unroll
  for (int off=32; off; off>>=1) se += __shfl_xor(se, off);
  if (lane==0) wvv[wid]=se;
  __syncthreads();
  float ex=0.f;
  if (tid<30){
    int c = sel[tid]; int seg=c/30; int bgc=bg[seg];
    bool nf = ((bgr!=0) ? (bgc==0) : (bgc!=0)) && (seg != r);
    if (!nf) ex = expf(2.0f*rowp[c]);        // positive not already in denom via neg
  }
  if (wid==0){
    #pragma unroll
    for (int off=32; off; off>>=1) ex += __shfl_xor(ex, off);
  }
  if (tid==0){
    float lse = logf(wvv[0]+wvv[1]+wvv[2]+wvv[3] + ex);
    float row = possum*(2.0f/30.0f) - lse;
    atomicAdd(out, -row*(1.0f/256.0f));
  }
}

extern "C" void kernel_launch(void* const* d_in, const int* in_sizes, int n_in,
                              void* d_out, int out_size, void* d_ws, size_t ws_size,
                              hipStream_t stream) {
  (void)in_sizes; (void)n_in; (void)out_size; (void)ws_size;
  const float* v1       = (const float*)d_in[0];
  const float* v2       = (const float*)d_in[1];
  const float* gq_w     = (const float*)d_in[2];
  const float* gq_gamma = (const float*)d_in[4];
  const float* gq_beta  = (const float*)d_in[5];
  const float* gk_w     = (const float*)d_in[6];
  const float* gk_gamma = (const float*)d_in[8];
  const float* gk_beta  = (const float*)d_in[9];
  const int*   idxs     = (const int*)d_in[12];
  const int*   bg       = (const int*)d_in[13];
  float* ws  = (float*)d_ws;
  float* out = (float*)d_out;

  hipMemsetAsync(ws, 0, (size_t)WS_ZERO_CNT*sizeof(float), stream);
  hipMemsetAsync(out, 0, sizeof(float), stream);

  wfrag_prep<<<2,64,0,stream>>>(gq_w, gk_w, ws+WS_WQF, ws+WS_WKF);
  head_stats_mfma<true ><<<2048,256,0,stream>>>(v2, ws+WS_WQF, ws+WS_GQ_PART, ws+WS_SEGX2);
  head_stats_mfma<false><<<2048,256,0,stream>>>(v1, ws+WS_WKF, ws+WS_GK_PART, nullptr);
  bn_params_kernel<<<1,192,0,stream>>>(gq_gamma, gq_beta, gk_gamma, gk_beta, ws);
  anchor_kernel<<<256,128,0,stream>>>(ws+WS_SEGX2, ws+WS_ANCHOR1);
  head_apply_mfma<<<2048,256,0,stream>>>(v2, ws+WS_WQF, ws+WS_GQ_SCALE, ws+WS_GQ_SHIFT, ws+WS_SEGG2);
  anchor_kernel<<<256,128,0,stream>>>(ws+WS_SEGG2, ws+WS_ANCHOR2);
  samples_kernel<<<240,192,0,stream>>>(v1, gk_w, ws+WS_GK_SCALE, ws+WS_GK_SHIFT, idxs,
                                       ws+WS_SAMPT, ws+WS_SAMP2T);
  sim2_mfma<<<dim3(30,16),256,0,stream>>>(ws+WS_ANCHOR2, ws+WS_SAMP2T, ws+WS_SROW);
  lcon1_kernel<<<256,64,0,stream>>>(ws+WS_ANCHOR1, ws+WS_SAMPT, out);
  lcon2_kernel<<<256,256,0,stream>>>(ws+WS_SROW, bg, out);
}

// Round 6
// 261.738 us; speedup vs baseline: 6.5697x; 1.3444x over previous
//
#include <hip/hip_runtime.h>
#include <math.h>

#define SK 7680          // 256 segments * 30 samples
#define NPTS 524288

// ---- workspace float offsets ----
#define WS_GQ_PART  0         // 32 partials x (96 sum + 96 sumsq)
#define WS_GK_PART  6144
#define WS_GQ_SCALE 12288
#define WS_GQ_SHIFT 12384
#define WS_GK_SCALE 12480
#define WS_GK_SHIFT 12576
#define WS_WQF      12672     // 18 frags x 64 lanes x 16B (bf16x8)
#define WS_WKF      17280
#define WS_SEGX2    21888     // 256*96 raw view2 segment sums
#define WS_SEGG2    46464     // 256*96 head(view2) segment sums
#define WS_ANCHOR1  71040
#define WS_ANCHOR2  95616
#define WS_SAMPT    120192    // [7680][96] raw l2normed samples (row-major)
#define WS_SAMP2T   857472    // [7680][96] head l2normed samples (row-major)
#define WS_SROW     1594752   // [256][7680] sim2 matrix
#define WS_ZERO_CNT 71040     // zero partials + seg sums (covers W frag bufs harmlessly)

typedef __attribute__((ext_vector_type(8))) short bf16x8;
typedef __attribute__((ext_vector_type(4))) float f32x4;

__device__ __forceinline__ ushort f2bf(float f){
  union { float f; unsigned u; } v; v.f = f;
  unsigned r = (v.u + 0x7fffu + ((v.u >> 16) & 1u)) >> 16;   // RNE
  return (ushort)r;
}
__device__ __forceinline__ bf16x8 pack8(float4 a, float4 b){
  bf16x8 r;
  r[0]=(short)f2bf(a.x); r[1]=(short)f2bf(a.y); r[2]=(short)f2bf(a.z); r[3]=(short)f2bf(a.w);
  r[4]=(short)f2bf(b.x); r[5]=(short)f2bf(b.y); r[6]=(short)f2bf(b.z); r[7]=(short)f2bf(b.w);
  return r;
}
__device__ __forceinline__ float4 ld4(const float* p){
  return *reinterpret_cast<const float4*>(p);
}

// ---- precompute bf16 W fragments: frag (kt,ot), lane l holds W[ot*16+(l&15)][kt*32+(l>>4)*8 + j]
__global__ __launch_bounds__(64) void wfrag_prep(
    const float* __restrict__ Wq, const float* __restrict__ Wk,
    float* __restrict__ outq, float* __restrict__ outk)
{
  const int l = threadIdx.x;
  const float* W  = blockIdx.x ? Wk : Wq;
  float* out      = blockIdx.x ? outk : outq;
  const int g = l >> 4, lr = l & 15;
  #pragma unroll
  for (int ot=0; ot<6; ++ot){
    const float* wr = W + (ot*16+lr)*96 + g*8;
    #pragma unroll
    for (int kt=0; kt<3; ++kt){
      bf16x8 f = pack8(ld4(wr + kt*32), ld4(wr + kt*32 + 4));
      *reinterpret_cast<bf16x8*>(out + ((kt*6+ot)*64 + l)*4) = f;
    }
  }
}

// stage 18KB of W fragments into LDS (layout preserved)
__device__ __forceinline__ void stage_wlds(const float* __restrict__ wfrag, float* wlds, int tid){
  #pragma unroll
  for (int i=0;i<5;i++){
    int idx = i*256 + tid;                       // float4 index, 1152 total
    if (idx < 1152)
      reinterpret_cast<float4*>(wlds)[idx] = reinterpret_cast<const float4*>(wfrag)[idx];
  }
}

// read 3 W fragments (kt=0,1,2) for one ot from LDS; serialized by lgkmcnt(0)
#define DS_W3(o0,o1,o2)                                             \
  asm volatile("ds_read_b128 %0, %3 offset:" #o0 "\n\t"             \
               "ds_read_b128 %1, %3 offset:" #o1 "\n\t"             \
               "ds_read_b128 %2, %3 offset:" #o2 "\n\t"             \
               "s_waitcnt lgkmcnt(0)"                               \
               : "=v"(w0), "=v"(w1), "=v"(w2) : "v"(wbase));        \
  __builtin_amdgcn_sched_barrier(0);

// ---- MFMA head pass 1: per-channel sum/sumsq of y = x @ W^T (bias cancels in BN),
// optionally fused raw-x per-segment sums. W fragments re-read from LDS (low VGPR, high occupancy).
template<bool DO_SEG>
__global__ __launch_bounds__(256) void head_stats_mfma(
    const float* __restrict__ X, const float* __restrict__ wfrag,
    float* __restrict__ gpart, float* __restrict__ gseg)
{
  __shared__ __align__(16) float wlds[4608];     // 18432 B
  __shared__ float red[192];
  __shared__ float rsg[96];
  const int tid = threadIdx.x;
  const int l = tid & 63, w = tid >> 6;
  const int g = l >> 4, lr = l & 15;

  stage_wlds(wfrag, wlds, tid);
  if (tid < 192) red[tid]=0.f;
  if (DO_SEG && tid < 96) rsg[tid]=0.f;
  __syncthreads();

  const unsigned wbase = (unsigned)(uintptr_t)wlds + (unsigned)(l*16);

  float sY[6], sY2[6];
  #pragma unroll
  for (int ot=0; ot<6; ++ot){ sY[ot]=0.f; sY2[ot]=0.f; }
  float rs[24];
  if (DO_SEG){
    #pragma unroll
    for (int t=0; t<24; ++t) rs[t]=0.f;
  }

  const long base_row = (long)blockIdx.x*256 + w*16 + lr;
  const float* xr0 = X + base_row*96 + g*8;

  #pragma unroll 1
  for (int it=0; it<4; ++it){
    const float* xr = xr0 + it*6144;             // +64 rows
    float4 c0=ld4(xr),    c1=ld4(xr+4);
    float4 c2=ld4(xr+32), c3=ld4(xr+36);
    float4 c4=ld4(xr+64), c5=ld4(xr+68);
    if (DO_SEG){
      rs[0]+=c0.x; rs[1]+=c0.y; rs[2]+=c0.z; rs[3]+=c0.w;
      rs[4]+=c1.x; rs[5]+=c1.y; rs[6]+=c1.z; rs[7]+=c1.w;
      rs[8]+=c2.x; rs[9]+=c2.y; rs[10]+=c2.z; rs[11]+=c2.w;
      rs[12]+=c3.x; rs[13]+=c3.y; rs[14]+=c3.z; rs[15]+=c3.w;
      rs[16]+=c4.x; rs[17]+=c4.y; rs[18]+=c4.z; rs[19]+=c4.w;
      rs[20]+=c5.x; rs[21]+=c5.y; rs[22]+=c5.z; rs[23]+=c5.w;
    }
    bf16x8 a0 = pack8(c0,c1), a1 = pack8(c2,c3), a2 = pack8(c4,c5);
    bf16x8 w0,w1,w2;
    {
      f32x4 acc={0.f,0.f,0.f,0.f};
      DS_W3(0,6144,12288)
      acc=__builtin_amdgcn_mfma_f32_16x16x32_bf16(a0,w0,acc,0,0,0);
      acc=__builtin_amdgcn_mfma_f32_16x16x32_bf16(a1,w1,acc,0,0,0);
      acc=__builtin_amdgcn_mfma_f32_16x16x32_bf16(a2,w2,acc,0,0,0);
      sY[0]+=acc[0]+acc[1]+acc[2]+acc[3];
      sY2[0]=fmaf(acc[0],acc[0],fmaf(acc[1],acc[1],fmaf(acc[2],acc[2],fmaf(acc[3],acc[3],sY2[0]))));
    }
    {
      f32x4 acc={0.f,0.f,0.f,0.f};
      DS_W3(1024,7168,13312)
      acc=__builtin_amdgcn_mfma_f32_16x16x32_bf16(a0,w0,acc,0,0,0);
      acc=__builtin_amdgcn_mfma_f32_16x16x32_bf16(a1,w1,acc,0,0,0);
      acc=__builtin_amdgcn_mfma_f32_16x16x32_bf16(a2,w2,acc,0,0,0);
      sY[1]+=acc[0]+acc[1]+acc[2]+acc[3];
      sY2[1]=fmaf(acc[0],acc[0],fmaf(acc[1],acc[1],fmaf(acc[2],acc[2],fmaf(acc[3],acc[3],sY2[1]))));
    }
    {
      f32x4 acc={0.f,0.f,0.f,0.f};
      DS_W3(2048,8192,14336)
      acc=__builtin_amdgcn_mfma_f32_16x16x32_bf16(a0,w0,acc,0,0,0);
      acc=__builtin_amdgcn_mfma_f32_16x16x32_bf16(a1,w1,acc,0,0,0);
      acc=__builtin_amdgcn_mfma_f32_16x16x32_bf16(a2,w2,acc,0,0,0);
      sY[2]+=acc[0]+acc[1]+acc[2]+acc[3];
      sY2[2]=fmaf(acc[0],acc[0],fmaf(acc[1],acc[1],fmaf(acc[2],acc[2],fmaf(acc[3],acc[3],sY2[2]))));
    }
    {
      f32x4 acc={0.f,0.f,0.f,0.f};
      DS_W3(3072,9216,15360)
      acc=__builtin_amdgcn_mfma_f32_16x16x32_bf16(a0,w0,acc,0,0,0);
      acc=__builtin_amdgcn_mfma_f32_16x16x32_bf16(a1,w1,acc,0,0,0);
      acc=__builtin_amdgcn_mfma_f32_16x16x32_bf16(a2,w2,acc,0,0,0);
      sY[3]+=acc[0]+acc[1]+acc[2]+acc[3];
      sY2[3]=fmaf(acc[0],acc[0],fmaf(acc[1],acc[1],fmaf(acc[2],acc[2],fmaf(acc[3],acc[3],sY2[3]))));
    }
    {
      f32x4 acc={0.f,0.f,0.f,0.f};
      DS_W3(4096,10240,16384)
      acc=__builtin_amdgcn_mfma_f32_16x16x32_bf16(a0,w0,acc,0,0,0);
      acc=__builtin_amdgcn_mfma_f32_16x16x32_bf16(a1,w1,acc,0,0,0);
      acc=__builtin_amdgcn_mfma_f32_16x16x32_bf16(a2,w2,acc,0,0,0);
      sY[4]+=acc[0]+acc[1]+acc[2]+acc[3];
      sY2[4]=fmaf(acc[0],acc[0],fmaf(acc[1],acc[1],fmaf(acc[2],acc[2],fmaf(acc[3],acc[3],sY2[4]))));
    }
    {
      f32x4 acc={0.f,0.f,0.f,0.f};
      DS_W3(5120,11264,17408)
      acc=__builtin_amdgcn_mfma_f32_16x16x32_bf16(a0,w0,acc,0,0,0);
      acc=__builtin_amdgcn_mfma_f32_16x16x32_bf16(a1,w1,acc,0,0,0);
      acc=__builtin_amdgcn_mfma_f32_16x16x32_bf16(a2,w2,acc,0,0,0);
      sY[5]+=acc[0]+acc[1]+acc[2]+acc[3];
      sY2[5]=fmaf(acc[0],acc[0],fmaf(acc[1],acc[1],fmaf(acc[2],acc[2],fmaf(acc[3],acc[3],sY2[5]))));
    }
  }

  #pragma unroll
  for (int ot=0; ot<6; ++ot){
    float s = sY[ot], s2 = sY2[ot];
    s  += __shfl_xor(s,16);  s  += __shfl_xor(s,32);
    s2 += __shfl_xor(s2,16); s2 += __shfl_xor(s2,32);
    if (g==0){
      atomicAdd(&red[ot*16+lr], s);
      atomicAdd(&red[96+ot*16+lr], s2);
    }
  }
  if (DO_SEG){
    #pragma unroll
    for (int t=0; t<24; ++t){
      float s = rs[t];
      s += __shfl_xor(s,1); s += __shfl_xor(s,2);
      s += __shfl_xor(s,4); s += __shfl_xor(s,8);
      if (lr==0){
        int kt = t>>3, j = t&7;
        atomicAdd(&rsg[kt*32 + g*8 + j], s);
      }
    }
  }
  __syncthreads();
  if (tid<96){
    float* dst = gpart + (blockIdx.x & 31)*192;   // 32-way de-contended partials
    atomicAdd(dst+tid,    red[tid]);
    atomicAdd(dst+96+tid, red[96+tid]);
    if (DO_SEG) atomicAdd(gseg + (blockIdx.x>>3)*96 + tid, rsg[tid]);
  }
}

// ---- MFMA head pass 2 (view2): relu(BN(y)) per-segment per-channel sums
__global__ __launch_bounds__(256) void head_apply_mfma(
    const float* __restrict__ X, const float* __restrict__ wfrag,
    const float* __restrict__ scale, const float* __restrict__ shift,
    float* __restrict__ gseg)
{
  __shared__ __align__(16) float wlds[4608];
  __shared__ float red[96];
  const int tid = threadIdx.x;
  const int l = tid & 63, w = tid >> 6;
  const int g = l >> 4, lr = l & 15;

  stage_wlds(wfrag, wlds, tid);
  if (tid < 96) red[tid]=0.f;
  __syncthreads();

  const unsigned wbase = (unsigned)(uintptr_t)wlds + (unsigned)(l*16);

  float sc[6], sh[6], zs[6];
  #pragma unroll
  for (int ot=0; ot<6; ++ot){
    sc[ot]=scale[ot*16+lr]; sh[ot]=shift[ot*16+lr]; zs[ot]=0.f;
  }

  const long base_row = (long)blockIdx.x*256 + w*16 + lr;
  const float* xr0 = X + base_row*96 + g*8;

  #pragma unroll 1
  for (int it=0; it<4; ++it){
    const float* xr = xr0 + it*6144;
    float4 c0=ld4(xr),    c1=ld4(xr+4);
    float4 c2=ld4(xr+32), c3=ld4(xr+36);
    float4 c4=ld4(xr+64), c5=ld4(xr+68);
    bf16x8 a0 = pack8(c0,c1), a1 = pack8(c2,c3), a2 = pack8(c4,c5);
    bf16x8 w0,w1,w2;
    {
      f32x4 acc={0.f,0.f,0.f,0.f};
      DS_W3(0,6144,12288)
      acc=__builtin_amdgcn_mfma_f32_16x16x32_bf16(a0,w0,acc,0,0,0);
      acc=__builtin_amdgcn_mfma_f32_16x16x32_bf16(a1,w1,acc,0,0,0);
      acc=__builtin_amdgcn_mfma_f32_16x16x32_bf16(a2,w2,acc,0,0,0);
      zs[0]+=fmaxf(fmaf(acc[0],sc[0],sh[0]),0.f)+fmaxf(fmaf(acc[1],sc[0],sh[0]),0.f)
            +fmaxf(fmaf(acc[2],sc[0],sh[0]),0.f)+fmaxf(fmaf(acc[3],sc[0],sh[0]),0.f);
    }
    {
      f32x4 acc={0.f,0.f,0.f,0.f};
      DS_W3(1024,7168,13312)
      acc=__builtin_amdgcn_mfma_f32_16x16x32_bf16(a0,w0,acc,0,0,0);
      acc=__builtin_amdgcn_mfma_f32_16x16x32_bf16(a1,w1,acc,0,0,0);
      acc=__builtin_amdgcn_mfma_f32_16x16x32_bf16(a2,w2,acc,0,0,0);
      zs[1]+=fmaxf(fmaf(acc[0],sc[1],sh[1]),0.f)+fmaxf(fmaf(acc[1],sc[1],sh[1]),0.f)
            +fmaxf(fmaf(acc[2],sc[1],sh[1]),0.f)+fmaxf(fmaf(acc[3],sc[1],sh[1]),0.f);
    }
    {
      f32x4 acc={0.f,0.f,0.f,0.f};
      DS_W3(2048,8192,14336)
      acc=__builtin_amdgcn_mfma_f32_16x16x32_bf16(a0,w0,acc,0,0,0);
      acc=__builtin_amdgcn_mfma_f32_16x16x32_bf16(a1,w1,acc,0,0,0);
      acc=__builtin_amdgcn_mfma_f32_16x16x32_bf16(a2,w2,acc,0,0,0);
      zs[2]+=fmaxf(fmaf(acc[0],sc[2],sh[2]),0.f)+fmaxf(fmaf(acc[1],sc[2],sh[2]),0.f)
            +fmaxf(fmaf(acc[2],sc[2],sh[2]),0.f)+fmaxf(fmaf(acc[3],sc[2],sh[2]),0.f);
    }
    {
      f32x4 acc={0.f,0.f,0.f,0.f};
      DS_W3(3072,9216,15360)
      acc=__builtin_amdgcn_mfma_f32_16x16x32_bf16(a0,w0,acc,0,0,0);
      acc=__builtin_amdgcn_mfma_f32_16x16x32_bf16(a1,w1,acc,0,0,0);
      acc=__builtin_amdgcn_mfma_f32_16x16x32_bf16(a2,w2,acc,0,0,0);
      zs[3]+=fmaxf(fmaf(acc[0],sc[3],sh[3]),0.f)+fmaxf(fmaf(acc[1],sc[3],sh[3]),0.f)
            +fmaxf(fmaf(acc[2],sc[3],sh[3]),0.f)+fmaxf(fmaf(acc[3],sc[3],sh[3]),0.f);
    }
    {
      f32x4 acc={0.f,0.f,0.f,0.f};
      DS_W3(4096,10240,16384)
      acc=__builtin_amdgcn_mfma_f32_16x16x32_bf16(a0,w0,acc,0,0,0);
      acc=__builtin_amdgcn_mfma_f32_16x16x32_bf16(a1,w1,acc,0,0,0);
      acc=__builtin_amdgcn_mfma_f32_16x16x32_bf16(a2,w2,acc,0,0,0);
      zs[4]+=fmaxf(fmaf(acc[0],sc[4],sh[4]),0.f)+fmaxf(fmaf(acc[1],sc[4],sh[4]),0.f)
            +fmaxf(fmaf(acc[2],sc[4],sh[4]),0.f)+fmaxf(fmaf(acc[3],sc[4],sh[4]),0.f);
    }
    {
      f32x4 acc={0.f,0.f,0.f,0.f};
      DS_W3(5120,11264,17408)
      acc=__builtin_amdgcn_mfma_f32_16x16x32_bf16(a0,w0,acc,0,0,0);
      acc=__builtin_amdgcn_mfma_f32_16x16x32_bf16(a1,w1,acc,0,0,0);
      acc=__builtin_amdgcn_mfma_f32_16x16x32_bf16(a2,w2,acc,0,0,0);
      zs[5]+=fmaxf(fmaf(acc[0],sc[5],sh[5]),0.f)+fmaxf(fmaf(acc[1],sc[5],sh[5]),0.f)
            +fmaxf(fmaf(acc[2],sc[5],sh[5]),0.f)+fmaxf(fmaf(acc[3],sc[5],sh[5]),0.f);
    }
  }

  #pragma unroll
  for (int ot=0; ot<6; ++ot){
    float s = zs[ot];
    s += __shfl_xor(s,16); s += __shfl_xor(s,32);
    if (g==0) atomicAdd(&red[ot*16+lr], s);
  }
  __syncthreads();
  if (tid<96) atomicAdd(gseg + (blockIdx.x>>3)*96 + tid, red[tid]);
}

// BN scale/shift from 32 partial sums (training-mode batch stats, biased var)
__global__ void bn_params_kernel(const float* __restrict__ gq_gamma, const float* __restrict__ gq_beta,
                                 const float* __restrict__ gk_gamma, const float* __restrict__ gk_beta,
                                 float* __restrict__ ws)
{
  const int t = threadIdx.x;
  const float invN = 1.0f/(float)NPTS;
  if (t < 96){
    float s=0.f, s2=0.f;
    #pragma unroll 4
    for (int p=0;p<32;p++){
      s  += ws[WS_GQ_PART + p*192 + t];
      s2 += ws[WS_GQ_PART + p*192 + 96 + t];
    }
    float mu  = s*invN;
    float var = s2*invN - mu*mu;
    float sc  = gq_gamma[t]*rsqrtf(var + 1e-5f);
    ws[WS_GQ_SCALE+t] = sc;
    ws[WS_GQ_SHIFT+t] = gq_beta[t] - mu*sc;
  } else if (t < 192){
    int c = t-96;
    float s=0.f, s2=0.f;
    #pragma unroll 4
    for (int p=0;p<32;p++){
      s  += ws[WS_GK_PART + p*192 + c];
      s2 += ws[WS_GK_PART + p*192 + 96 + c];
    }
    float mu  = s*invN;
    float var = s2*invN - mu*mu;
    float sc  = gk_gamma[c]*rsqrtf(var + 1e-5f);
    ws[WS_GK_SCALE+c] = sc;
    ws[WS_GK_SHIFT+c] = gk_beta[c] - mu*sc;
  }
}

// anchor = l2norm(segsum/2048)
__global__ __launch_bounds__(128) void anchor_kernel(
    const float* __restrict__ segsum, float* __restrict__ dst)
{
  __shared__ float red[128];
  const int t = threadIdx.x, s = blockIdx.x;
  float m = 0.f;
  if (t<96) m = segsum[s*96+t] * (1.0f/2048.0f);
  red[t] = m*m;
  __syncthreads();
  for (int off=64; off>0; off>>=1){
    if (t<off) red[t]+=red[t+off];
    __syncthreads();
  }
  float inv = 1.0f/(sqrtf(red[0]) + 1e-7f);
  if (t<96) dst[s*96+t] = m*inv;
}

// ---- fp32 96x96 tile GEMM helpers (used only by samples_kernel) ----
__device__ __forceinline__ void fma_row(float4& acc, const float4 x,
    const float4 w0, const float4 w1, const float4 w2, const float4 w3){
  acc.x = fmaf(x.x,w0.x, fmaf(x.y,w1.x, fmaf(x.z,w2.x, fmaf(x.w,w3.x, acc.x))));
  acc.y = fmaf(x.x,w0.y, fmaf(x.y,w1.y, fmaf(x.z,w2.y, fmaf(x.w,w3.y, acc.y))));
  acc.z = fmaf(x.x,w0.z, fmaf(x.y,w1.z, fmaf(x.z,w2.z, fmaf(x.w,w3.z, acc.z))));
  acc.w = fmaf(x.x,w0.w, fmaf(x.y,w1.w, fmaf(x.z,w2.w, fmaf(x.w,w3.w, acc.w))));
}
__device__ __forceinline__ void load_W(const float* __restrict__ W, float* Ws, int tid){
  #pragma unroll
  for (int i=0;i<12;i++){
    int f = i*768 + tid*4;
    int oc = f/96, k = f%96;
    float4 w4 = *reinterpret_cast<const float4*>(W + f);
    Ws[(k+0)*100+oc]=w4.x; Ws[(k+1)*100+oc]=w4.y;
    Ws[(k+2)*100+oc]=w4.z; Ws[(k+3)*100+oc]=w4.w;
  }
}
__device__ __forceinline__ void gemm_tile(const float* Xs, const float* Ws,
    int ocg, int rowg, int r0, float4 acc[4]){
  const float4* Xs4 = reinterpret_cast<const float4*>(Xs);
  const float4* Ws4 = reinterpret_cast<const float4*>(Ws);
  acc[0]=acc[1]=acc[2]=acc[3]=make_float4(0.f,0.f,0.f,0.f);
  #pragma unroll 4
  for (int k4=0;k4<24;k4++){
    float4 w0 = Ws4[(k4*4+0)*25 + ocg];
    float4 w1 = Ws4[(k4*4+1)*25 + ocg];
    float4 w2 = Ws4[(k4*4+2)*25 + ocg];
    float4 w3 = Ws4[(k4*4+3)*25 + ocg];
    #pragma unroll
    for (int jj=0;jj<4;jj++){
      float4 xv = Xs4[(r0+jj)*25 + (k4 ^ rowg)];
      fma_row(acc[jj], xv, w0, w1, w2, w3);
    }
  }
}

// gather 32 sampled view1 rows -> raw l2norm + gk-head l2norm, stored ROW-MAJOR [7680][96]
__global__ __launch_bounds__(192) void samples_kernel(
    const float* __restrict__ V1, const float* __restrict__ W,
    const float* __restrict__ scale, const float* __restrict__ shift,
    const int* __restrict__ idxs,
    float* __restrict__ sampT, float* __restrict__ samp2T)
{
  __shared__ __align__(16) float Ws[9600];
  __shared__ __align__(16) float Xs[3200];
  __shared__ __align__(16) float Gs[3200];
  __shared__ float invr[32], invh[32];
  const int tid = threadIdx.x;
  const int ocg = tid % 24, rowg = tid / 24;
  const int oc0 = ocg*4,  r0  = rowg*4;
  load_W(W, Ws, tid);
  const int base = blockIdx.x * 32;
  #pragma unroll
  for (int i=0;i<4;i++){
    int f = i*768 + tid*4;
    int row = f/96, col = f%96;
    int g = idxs[base+row];
    float4 v = *reinterpret_cast<const float4*>(V1 + g*96 + col);
    *reinterpret_cast<float4*>(Xs + row*100 + (col ^ ((row>>2)<<2))) = v;
  }
  __syncthreads();
  if (tid<32){
    float s=0.f;
    #pragma unroll
    for (int k=0;k<96;k++){ float v=Xs[tid*100+(k^((tid>>2)<<2))]; s=fmaf(v,v,s); }
    invr[tid]=1.0f/(sqrtf(s)+1e-7f);
  }
  __syncthreads();
  {
    int rr=tid&31, kg=tid>>5;
    float inv=invr[rr];
    #pragma unroll
    for (int kk=0;kk<16;kk++){
      int k=kg*16+kk;
      sampT[(long)(base+rr)*96 + k] = Xs[rr*100 + (k ^ ((rr>>2)<<2))]*inv;
    }
  }
  float4 acc[4];
  gemm_tile(Xs, Ws, ocg, rowg, r0, acc);
  float4 sc = make_float4(scale[oc0],scale[oc0+1],scale[oc0+2],scale[oc0+3]);
  float4 sh = make_float4(shift[oc0],shift[oc0+1],shift[oc0+2],shift[oc0+3]);
  #pragma unroll
  for (int jj=0;jj<4;jj++){
    int rr=r0+jj;
    float4 g;
    g.x=fmaxf(fmaf(acc[jj].x,sc.x,sh.x),0.f);
    g.y=fmaxf(fmaf(acc[jj].y,sc.y,sh.y),0.f);
    g.z=fmaxf(fmaf(acc[jj].z,sc.z,sh.z),0.f);
    g.w=fmaxf(fmaf(acc[jj].w,sc.w,sh.w),0.f);
    *reinterpret_cast<float4*>(Gs + rr*100 + (oc0 ^ ((rr>>2)<<2))) = g;
  }
  __syncthreads();
  if (tid<32){
    float s=0.f;
    #pragma unroll
    for (int k=0;k<96;k++){ float v=Gs[tid*100+(k^((tid>>2)<<2))]; s=fmaf(v,v,s); }
    invh[tid]=1.0f/(sqrtf(s)+1e-7f);
  }
  __syncthreads();
  {
    int rr=tid&31, kg=tid>>5;
    float inv=invh[rr];
    #pragma unroll
    for (int kk=0;kk<16;kk++){
      int k=kg*16+kk;
      samp2T[(long)(base+rr)*96 + k] = Gs[rr*100 + (k ^ ((rr>>2)<<2))]*inv;
    }
  }
}

// ---- sim2 = anchor2 @ samples2^T via MFMA: grid (30 col-tiles, 16 row-tiles) ----
__global__ __launch_bounds__(256) void sim2_mfma(
    const float* __restrict__ anchor2, const float* __restrict__ samp2,  // samp2 [7680][96]
    float* __restrict__ srowG)
{
  const int tid = threadIdx.x;
  const int l = tid & 63, w = tid >> 6;
  const int g = l >> 4, lr = l & 15;
  const int rowbase = blockIdx.y * 16;
  const int colbase = blockIdx.x * 256 + w * 64;

  bf16x8 af[3];
  const float* ar = anchor2 + (rowbase + lr)*96 + g*8;
  #pragma unroll
  for (int kt=0; kt<3; ++kt)
    af[kt] = pack8(ld4(ar + kt*32), ld4(ar + kt*32 + 4));

  #pragma unroll
  for (int sub=0; sub<4; ++sub){
    const float* br = samp2 + (long)(colbase + sub*16 + lr)*96 + g*8;
    float4 b00 = ld4(br);    float4 b01 = ld4(br+4);
    float4 b10 = ld4(br+32); float4 b11 = ld4(br+36);
    float4 b20 = ld4(br+64); float4 b21 = ld4(br+68);
    f32x4 acc = {0.f,0.f,0.f,0.f};
    acc = __builtin_amdgcn_mfma_f32_16x16x32_bf16(af[0], pack8(b00,b01), acc, 0,0,0);
    acc = __builtin_amdgcn_mfma_f32_16x16x32_bf16(af[1], pack8(b10,b11), acc, 0,0,0);
    acc = __builtin_amdgcn_mfma_f32_16x16x32_bf16(af[2], pack8(b20,b21), acc, 0,0,0);
    const int col  = colbase + sub*16 + lr;
    const int row0 = rowbase + g*4;
    #pragma unroll
    for (int i=0;i<4;i++)
      srowG[(long)(row0+i)*SK + col] = acc[i];
  }
}

// Lcon: 60 relevant columns per row (30 diag positives + 30 linspace negatives)
__global__ __launch_bounds__(64) void lcon1_kernel(
    const float* __restrict__ anchor, const float* __restrict__ sampT, float* __restrict__ out)
{
  __shared__ float a[96];
  const int tid = threadIdx.x, r = blockIdx.x;
  for (int i=tid;i<96;i+=64) a[i]=anchor[r*96+i];
  __syncthreads();
  int c = 0;
  if (tid<30) c = r*30+tid;
  else if (tid<60){
    int j = tid-30;
    int p = (int)((double)j * 7649.0 / 29.0);   // linspace(0, M-1, 30).astype(int32)
    c = (p < r*30) ? p : p+30;                  // skip own block
  }
  float s=0.f;
  if (tid<60){
    const float* sr = sampT + (long)c*96;
    #pragma unroll
    for (int k4=0;k4<24;k4++){
      float4 v = *reinterpret_cast<const float4*>(sr + k4*4);
      s = fmaf(a[k4*4+0],v.x, fmaf(a[k4*4+1],v.y,
          fmaf(a[k4*4+2],v.z, fmaf(a[k4*4+3],v.w, s))));
    }
  }
  float logit = 2.0f*s;                          // /T, T=0.5
  float se = (tid<60) ? expf(logit) : 0.f;
  float sp = (tid<30) ? logit : 0.f;
  #pragma unroll
  for (int off=32; off; off>>=1){ se += __shfl_xor(se,off); sp += __shfl_xor(sp,off); }
  if (tid==0){
    float row = sp*(1.0f/30.0f) - logf(se);
    atomicAdd(out, -row*(1.0f/256.0f));
  }
}

// Lcon2 selection/softmax over precomputed sim2 row
__global__ __launch_bounds__(256) void lcon2_kernel(
    const float* __restrict__ srowG, const int* __restrict__ bg, float* __restrict__ out)
{
  __shared__ float wvv[4];
  __shared__ int   wcc[4];
  __shared__ int   winc_s;
  __shared__ int   sel[30];
  const int tid = threadIdx.x, r = blockIdx.x;
  const int lane = tid & 63, wid = tid >> 6;
  const float* __restrict__ rowp = srowG + (long)r*SK;
  float val[30];
  #pragma unroll
  for (int j=0;j<30;j++) val[j] = rowp[(j<<8) + tid];
  unsigned mask=0; float possum=0.f;
  for (int it=0; it<30; ++it){
    float bv = -3.0e38f; int bc = 1<<30;
    #pragma unroll
    for (int j=0;j<30;j++){
      if (!((mask>>j)&1u)){
        float v = val[j]; int c = tid + (j<<8);
        if (v > bv || (v == bv && c < bc)){ bv=v; bc=c; }
      }
    }
    #pragma unroll
    for (int off=32; off; off>>=1){
      float ov = __shfl_xor(bv, off); int ocx = __shfl_xor(bc, off);
      if (ov > bv || (ov == bv && ocx < bc)){ bv=ov; bc=ocx; }
    }
    if (lane==0){ wvv[wid]=bv; wcc[wid]=bc; }
    __syncthreads();
    if (tid==0){
      float v=wvv[0]; int c=wcc[0];
      #pragma unroll
      for (int w=1;w<4;w++){
        if (wvv[w]>v || (wvv[w]==v && wcc[w]<c)){ v=wvv[w]; c=wcc[w]; }
      }
      winc_s=c; sel[it]=c; possum += v;
    }
    __syncthreads();
    int c = winc_s;
    if ((c & 255) == tid) mask |= 1u << (c >> 8);
  }
  const int bgr = bg[r];
  float se=0.f;
  #pragma unroll
  for (int j=0;j<30;j++){
    int c = tid + (j<<8);
    int seg = c/30;
    int bgc = bg[seg];
    bool nf = ((bgr!=0) ? (bgc==0) : (bgc!=0)) && (seg != r);
    if (nf) se += expf(2.0f*val[j]);
  }
  #pragma unroll
  for (int off=32; off; off>>=1) se += __shfl_xor(se, off);
  if (lane==0) wvv[wid]=se;
  __syncthreads();
  float ex=0.f;
  if (tid<30){
    int c = sel[tid]; int seg=c/30; int bgc=bg[seg];
    bool nf = ((bgr!=0) ? (bgc==0) : (bgc!=0)) && (seg != r);
    if (!nf) ex = expf(2.0f*rowp[c]);        // positive not already in denom via neg
  }
  if (wid==0){
    #pragma unroll
    for (int off=32; off; off>>=1) ex += __shfl_xor(ex, off);
  }
  if (tid==0){
    float lse = logf(wvv[0]+wvv[1]+wvv[2]+wvv[3] + ex);
    float row = possum*(2.0f/30.0f) - lse;
    atomicAdd(out, -row*(1.0f/256.0f));
  }
}

extern "C" void kernel_launch(void* const* d_in, const int* in_sizes, int n_in,
                              void* d_out, int out_size, void* d_ws, size_t ws_size,
                              hipStream_t stream) {
  (void)in_sizes; (void)n_in; (void)out_size; (void)ws_size;
  const float* v1       = (const float*)d_in[0];
  const float* v2       = (const float*)d_in[1];
  const float* gq_w     = (const float*)d_in[2];
  const float* gq_gamma = (const float*)d_in[4];
  const float* gq_beta  = (const float*)d_in[5];
  const float* gk_w     = (const float*)d_in[6];
  const float* gk_gamma = (const float*)d_in[8];
  const float* gk_beta  = (const float*)d_in[9];
  const int*   idxs     = (const int*)d_in[12];
  const int*   bg       = (const int*)d_in[13];
  float* ws  = (float*)d_ws;
  float* out = (float*)d_out;

  hipMemsetAsync(ws, 0, (size_t)WS_ZERO_CNT*sizeof(float), stream);
  hipMemsetAsync(out, 0, sizeof(float), stream);

  wfrag_prep<<<2,64,0,stream>>>(gq_w, gk_w, ws+WS_WQF, ws+WS_WKF);
  head_stats_mfma<true ><<<2048,256,0,stream>>>(v2, ws+WS_WQF, ws+WS_GQ_PART, ws+WS_SEGX2);
  head_stats_mfma<false><<<2048,256,0,stream>>>(v1, ws+WS_WKF, ws+WS_GK_PART, nullptr);
  bn_params_kernel<<<1,192,0,stream>>>(gq_gamma, gq_beta, gk_gamma, gk_beta, ws);
  anchor_kernel<<<256,128,0,stream>>>(ws+WS_SEGX2, ws+WS_ANCHOR1);
  head_apply_mfma<<<2048,256,0,stream>>>(v2, ws+WS_WQF, ws+WS_GQ_SCALE, ws+WS_GQ_SHIFT, ws+WS_SEGG2);
  anchor_kernel<<<256,128,0,stream>>>(ws+WS_SEGG2, ws+WS_ANCHOR2);
  samples_kernel<<<240,192,0,stream>>>(v1, gk_w, ws+WS_GK_SCALE, ws+WS_GK_SHIFT, idxs,
                                       ws+WS_SAMPT, ws+WS_SAMP2T);
  sim2_mfma<<<dim3(30,16),256,0,stream>>>(ws+WS_ANCHOR2, ws+WS_SAMP2T, ws+WS_SROW);
  lcon1_kernel<<<256,64,0,stream>>>(ws+WS_ANCHOR1, ws+WS_SAMPT, out);
  lcon2_kernel<<<256,256,0,stream>>>(ws+WS_SROW, bg, out);
}